// Round 2
// baseline (647.963 us; speedup 1.0000x reference)
//
#include <hip/hip_runtime.h>
#include <math.h>

// SplashEncoding: 16-level hash grid, trilinear interp; levels 14/15 add
// Gaussian splash mixtures (ns=2/4) feeding both feature and GMM outputs.
//
// R2 changes vs R1 (302us, FETCH 661MB, latency-bound):
//  - repack L14/L15 (means/stds/feats) into AoS slots in d_ws: 1-2 lines/corner
//    instead of 3-5, nontemporal loads (streaming; protect L2 for small tables)
//  - XCD-affinity worklist: hashed 1MB tables (levels 4-13) pinned to one XCD
//    each via blockIdx%8 round-robin heuristic -> L2-resident (~200cyc vs 400+)
//  - levels 0-3/14/15 spread across XCDs, cost-weighted for balance

#define HMASK 131071
typedef float vf4 __attribute__((ext_vector_type(4)));

__constant__ int c_res[16] = {16,23,34,50,74,109,161,237,348,512,753,1108,1629,2394,3520,5174};
__constant__ int c_fb[16]  = {0,4096,16263,55567,180567,311639,442711,573783,704855,835927,
                              966999,1098071,1229143,1360215,1491287,1753431};
// shared-level stream: levels {0,1,2,3,14,15} interleaved, chunk = s/6
__constant__ int c_sl[6]  = {0,1,2,3,14,15};
// per-XCD: pinned item count, shared-stream start, total items
// X0:{4,12} X1:{5,13} X2..7:{6..11}; shared shares 384,384,896x6 (cost-balanced)
__constant__ int c_pc[8]  = {2048,2048,1024,1024,1024,1024,1024,1024};
__constant__ int c_ss[8]  = {0,384,768,1664,2560,3456,4352,5248};
__constant__ int c_tot[8] = {2432,2432,1920,1920,1920,1920,1920,1920};

__device__ __forceinline__ void corner_setup(int res, float cx, float cy, float cz,
                                             int& px, int& py, int& pz,
                                             float& fx, float& fy, float& fz)
{
    const float hi = (float)((double)res - 1.001);   // matches jnp.clip(res*c, 0, res-1.001)
    float x = fminf(fmaxf((float)res * cx, 0.0f), hi);
    float y = fminf(fmaxf((float)res * cy, 0.0f), hi);
    float z = fminf(fmaxf((float)res * cz, 0.0f), hi);
    px = (int)x; py = (int)y; pz = (int)z;           // >=0 so trunc == floor
    fx = x - (float)px; fy = y - (float)py; fz = z - (float)pz;
}

template<bool HASH>
__device__ __forceinline__ void plain_level(
    int n, int level, int res, int fbase,
    float cx, float cy, float cz,
    const float* __restrict__ feats, float* __restrict__ out)
{
    int px, py, pz; float fx, fy, fz;
    corner_setup(res, cx, cy, cz, px, py, pz, fx, fy, fz);

    int   idxs[8];
    float ws[8];
#pragma unroll
    for (int k = 0; k < 8; ++k) {
        const int ox = (k >> 2) & 1, oy = (k >> 1) & 1, oz = k & 1;
        const int ix = px + ox, iy = py + oy, iz = pz + oz;
        ws[k] = (ox ? fx : 1.0f - fx) * (oy ? fy : 1.0f - fy) * (oz ? fz : 1.0f - fz);
        if (HASH) {
            unsigned h = (unsigned)ix ^ ((unsigned)iy * 2654435761u) ^ ((unsigned)iz * 805459861u);
            idxs[k] = (int)(h & HMASK);
        } else {
            idxs[k] = ix + iy * res + iz * res * res;
        }
    }
    float2 fv[8];
#pragma unroll
    for (int k = 0; k < 8; ++k)
        fv[k] = *(const float2*)(feats + (size_t)(fbase + idxs[k]) * 2);

    float a0 = 0.0f, a1 = 0.0f;
#pragma unroll
    for (int k = 0; k < 8; ++k) { a0 += ws[k] * fv[k].x; a1 += ws[k] * fv[k].y; }

    *(float2*)(out + (size_t)n * 32 + 2 * level) = make_float2(a0, a1);
}

__device__ __forceinline__ void gauss_term(float w, float cx, float cy, float cz,
                                           float mx, float my, float mz, float sraw,
                                           float f0, float f1,
                                           float& a0, float& a1, float& ag)
{
    const float dx = cx - mx, dy = cy - my, dz = cz - mz;
    const float sva = fabsf(sraw);
    const float d2 = dx*dx + dy*dy + dz*dz;
    const float s2 = sva * sva;
    const float sq = d2 / (2.0f * s2 + 1e-7f);
    const float gw = expf(-sq) / (2.5066282746310002f * sva + 1e-7f);
    const float wg = w * gw;
    a0 += wg * f0;
    a1 += wg * f1;
    ag += wg * (d2 / s2);
}

// ---- packed splash: slots hold [m0.xyz s0][f0.xy m1.xy][m1.z s1 f1.xy] (x2 for NS=4)
template<int NS>
__device__ __forceinline__ void splash_packed(
    int n, int level, int res,
    float cx, float cy, float cz,
    const vf4* __restrict__ slots, float* __restrict__ out, float* __restrict__ gmm)
{
    int px, py, pz; float fx, fy, fz;
    corner_setup(res, cx, cy, cz, px, py, pz, fx, fy, fz);

    float a0 = 0.0f, a1 = 0.0f, ag = 0.0f;
#pragma unroll
    for (int k = 0; k < 8; ++k) {
        const int ox = (k >> 2) & 1, oy = (k >> 1) & 1, oz = k & 1;
        const int ix = px + ox, iy = py + oy, iz = pz + oz;
        const float w = (ox ? fx : 1.0f - fx) * (oy ? fy : 1.0f - fy) * (oz ? fz : 1.0f - fz);
        unsigned h = (unsigned)ix ^ ((unsigned)iy * 2654435761u) ^ ((unsigned)iz * 805459861u);
        const int idx = (int)(h & HMASK);
        const vf4* sp = slots + (size_t)idx * (NS == 2 ? 4 : 8);

        vf4 w0 = __builtin_nontemporal_load(sp + 0);
        vf4 w1 = __builtin_nontemporal_load(sp + 1);
        vf4 w2 = __builtin_nontemporal_load(sp + 2);
        gauss_term(w, cx, cy, cz, w0.x, w0.y, w0.z, w0.w, w1.x, w1.y, a0, a1, ag);
        gauss_term(w, cx, cy, cz, w1.z, w1.w, w2.x, w2.y, w2.z, w2.w, a0, a1, ag);
        if (NS == 4) {
            vf4 w3 = __builtin_nontemporal_load(sp + 3);
            vf4 w4 = __builtin_nontemporal_load(sp + 4);
            vf4 w5 = __builtin_nontemporal_load(sp + 5);
            gauss_term(w, cx, cy, cz, w3.x, w3.y, w3.z, w3.w, w4.x, w4.y, a0, a1, ag);
            gauss_term(w, cx, cy, cz, w4.z, w4.w, w5.x, w5.y, w5.z, w5.w, a0, a1, ag);
        }
    }
    *(float2*)(out + (size_t)n * 32 + 2 * level) = make_float2(a0, a1);
    gmm[n * 2 + (level - 14)] = ag;
}

// ---- fallback splash (direct table loads), identical to R1
template<int NS>
__device__ __forceinline__ void splash_direct(
    int n, int level, int res, int fbase, int gbase,
    float cx, float cy, float cz,
    const float* __restrict__ feats, const float* __restrict__ means,
    const float* __restrict__ stds, float* __restrict__ out, float* __restrict__ gmm)
{
    int px, py, pz; float fx, fy, fz;
    corner_setup(res, cx, cy, cz, px, py, pz, fx, fy, fz);

    float a0 = 0.0f, a1 = 0.0f, ag = 0.0f;
#pragma unroll
    for (int k = 0; k < 8; ++k) {
        const int ox = (k >> 2) & 1, oy = (k >> 1) & 1, oz = k & 1;
        const int ix = px + ox, iy = py + oy, iz = pz + oz;
        const float w = (ox ? fx : 1.0f - fx) * (oy ? fy : 1.0f - fy) * (oz ? fz : 1.0f - fz);
        unsigned h = (unsigned)ix ^ ((unsigned)iy * 2654435761u) ^ ((unsigned)iz * 805459861u);
        const int idx = (int)(h & HMASK);
        const int grow = gbase + idx * NS;

        const float* m = means + (size_t)grow * 3;
        const float* s = stds + grow;
        const float* f = feats + (size_t)(fbase + idx * NS) * 2;
#pragma unroll
        for (int si = 0; si < NS; ++si)
            gauss_term(w, cx, cy, cz, m[3*si], m[3*si+1], m[3*si+2], s[si],
                       f[2*si], f[2*si+1], a0, a1, ag);
    }
    *(float2*)(out + (size_t)n * 32 + 2 * level) = make_float2(a0, a1);
    gmm[n * 2 + (level - 14)] = ag;
}

// ---- repack means/stds/feats of levels 14/15 into AoS slots in ws
__global__ __launch_bounds__(256) void repack_kernel(
    const float* __restrict__ means, const float* __restrict__ stds,
    const float* __restrict__ feats, float* __restrict__ ws)
{
    const int i = blockIdx.x * 256 + threadIdx.x;     // 0 .. 262143
    if (i < 131072) {
        // level 14: ns=2, gbase=0, fbase=1491287
        const int grow = i * 2;
        const float* m = means + (size_t)grow * 3;
        const float* f = feats + (size_t)(1491287 + grow) * 2;
        const float s0 = stds[grow], s1 = stds[grow + 1];
        vf4* dst = (vf4*)ws + (size_t)i * 4;          // 64B slot
        dst[0] = (vf4){m[0], m[1], m[2], s0};
        dst[1] = (vf4){f[0], f[1], m[3], m[4]};
        dst[2] = (vf4){m[5], s1, f[2], f[3]};
    } else {
        // level 15: ns=4, gbase=262144, fbase=1753431
        const int j = i - 131072;
        const int grow = 262144 + j * 4;
        const float* m = means + (size_t)grow * 3;
        const float* s = stds + grow;
        const float* f = feats + (size_t)(1753431 + j * 4) * 2;
        vf4* dst = (vf4*)ws + 524288 + (size_t)j * 8; // after 8MB L14 region; 128B slot
        dst[0] = (vf4){m[0], m[1], m[2], s[0]};
        dst[1] = (vf4){f[0], f[1], m[3], m[4]};
        dst[2] = (vf4){m[5], s[1], f[2], f[3]};
        dst[3] = (vf4){m[6], m[7], m[8], s[2]};
        dst[4] = (vf4){f[4], f[5], m[9], m[10]};
        dst[5] = (vf4){m[11], s[3], f[6], f[7]};
    }
}

template<bool PACKED>
__global__ __launch_bounds__(256) void splash_main(
    const float* __restrict__ coords, const float* __restrict__ feats,
    const float* __restrict__ means,  const float* __restrict__ stds,
    const float* __restrict__ ws, float* __restrict__ out, int N)
{
    const int x   = blockIdx.x & 7;      // presumed XCD (round-robin heuristic)
    const int j   = blockIdx.x >> 3;     // block-within-XCD
    const int tid = threadIdx.x;
    float* gmm = out + (size_t)N * 32;
    const int tot = c_tot[x], pc = c_pc[x], ss = c_ss[x];

    for (int i = j; i < tot; i += 512) {
        int level, chunk;
        if (i < pc) {                    // pinned hashed levels 4..13
            level = (i < 1024) ? 4 + x : 12 + x;
            chunk = i & 1023;
        } else {                         // shared stream: levels 0-3, 14, 15
            const int s = ss + (i - pc);
            level = c_sl[s % 6];
            chunk = s / 6;
        }
        const int n = chunk * 256 + tid;
        if (n >= N) continue;
        const float cx = coords[3*n+0], cy = coords[3*n+1], cz = coords[3*n+2];
        const int res = c_res[level];
        const int fbase = c_fb[level];

        if (level < 4) {
            plain_level<false>(n, level, res, fbase, cx, cy, cz, feats, out);
        } else if (level < 14) {
            plain_level<true>(n, level, res, fbase, cx, cy, cz, feats, out);
        } else if (level == 14) {
            if (PACKED) splash_packed<2>(n, level, res, cx, cy, cz, (const vf4*)ws, out, gmm);
            else        splash_direct<2>(n, level, res, fbase, 0, cx, cy, cz, feats, means, stds, out, gmm);
        } else {
            if (PACKED) splash_packed<4>(n, level, res, cx, cy, cz, (const vf4*)ws + 524288, out, gmm);
            else        splash_direct<4>(n, level, res, fbase, 262144, cx, cy, cz, feats, means, stds, out, gmm);
        }
    }
}

extern "C" void kernel_launch(void* const* d_in, const int* in_sizes, int n_in,
                              void* d_out, int out_size, void* d_ws, size_t ws_size,
                              hipStream_t stream) {
    const float* coords = (const float*)d_in[0];
    const float* feats  = (const float*)d_in[1];
    const float* means  = (const float*)d_in[2];
    const float* stds   = (const float*)d_in[3];
    float* out = (float*)d_out;
    const int N = in_sizes[0] / 3;   // 262144

    const bool packed = (ws_size >= 25165824);   // 8MB + 16MB slot regions
    if (packed) {
        repack_kernel<<<1024, 256, 0, stream>>>(means, stds, feats, (float*)d_ws);
        splash_main<true><<<4096, 256, 0, stream>>>(coords, feats, means, stds,
                                                    (const float*)d_ws, out, N);
    } else {
        splash_main<false><<<4096, 256, 0, stream>>>(coords, feats, means, stds,
                                                     (const float*)d_ws, out, N);
    }
}

// Round 3
// 282.717 us; speedup vs baseline: 2.2919x; 2.2919x over previous
//
#include <hip/hip_runtime.h>
#include <math.h>

// SplashEncoding: 16-level hash grid, trilinear interp; levels 14/15 add
// Gaussian splash mixtures (ns=2/4) feeding both feature and GMM outputs.
//
// R3 vs R2 (588us FAIL — NT loads destroyed 16x table reuse; worklist cut
// occupancy):
//  - back to flat grid; thread = (point, half): half h does levels 8h..8h+7
//    into registers, writes ONE full 64B line -> kills the 4x write
//    amplification R1 showed (WRITE 135MB vs 36MB ideal)
//  - keep L14/L15 AoS repack (1 line/corner L14, 2 lines L15) but with
//    REGULAR cached loads (tables have 16x reuse; NT was the R2 mistake)
//  - L15 slot padded to 2 independent 64B lines: [g0,g1|pad][g2,g3|pad]

#define HMASK 131071
typedef float vf4 __attribute__((ext_vector_type(4)));

__device__ __forceinline__ void corner_setup(int res, float cx, float cy, float cz,
                                             int& px, int& py, int& pz,
                                             float& fx, float& fy, float& fz)
{
    const float hi = (float)((double)res - 1.001);   // matches jnp.clip(res*c, 0, res-1.001)
    float x = fminf(fmaxf((float)res * cx, 0.0f), hi);
    float y = fminf(fmaxf((float)res * cy, 0.0f), hi);
    float z = fminf(fmaxf((float)res * cz, 0.0f), hi);
    px = (int)x; py = (int)y; pz = (int)z;           // >=0 so trunc == floor
    fx = x - (float)px; fy = y - (float)py; fz = z - (float)pz;
}

template<bool HASH>
__device__ __forceinline__ float2 plain_eval(
    int res, int fbase, float cx, float cy, float cz,
    const float* __restrict__ feats)
{
    int px, py, pz; float fx, fy, fz;
    corner_setup(res, cx, cy, cz, px, py, pz, fx, fy, fz);

    int   idxs[8];
    float ws[8];
#pragma unroll
    for (int k = 0; k < 8; ++k) {
        const int ox = (k >> 2) & 1, oy = (k >> 1) & 1, oz = k & 1;
        const int ix = px + ox, iy = py + oy, iz = pz + oz;
        ws[k] = (ox ? fx : 1.0f - fx) * (oy ? fy : 1.0f - fy) * (oz ? fz : 1.0f - fz);
        if (HASH) {
            unsigned h = (unsigned)ix ^ ((unsigned)iy * 2654435761u) ^ ((unsigned)iz * 805459861u);
            idxs[k] = (int)(h & HMASK);
        } else {
            idxs[k] = ix + iy * res + iz * res * res;
        }
    }
    float2 fv[8];      // batch the 8 gathers for memory-level parallelism
#pragma unroll
    for (int k = 0; k < 8; ++k)
        fv[k] = *(const float2*)(feats + (size_t)(fbase + idxs[k]) * 2);

    float a0 = 0.0f, a1 = 0.0f;
#pragma unroll
    for (int k = 0; k < 8; ++k) { a0 += ws[k] * fv[k].x; a1 += ws[k] * fv[k].y; }
    return make_float2(a0, a1);
}

__device__ __forceinline__ void gauss_term(float w, float cx, float cy, float cz,
                                           float mx, float my, float mz, float sraw,
                                           float f0, float f1,
                                           float& a0, float& a1, float& ag)
{
    const float dx = cx - mx, dy = cy - my, dz = cz - mz;
    const float sva = fabsf(sraw);
    const float d2 = dx*dx + dy*dy + dz*dz;
    const float s2 = sva * sva;
    const float sq = d2 / (2.0f * s2 + 1e-7f);
    const float gw = expf(-sq) / (2.5066282746310002f * sva + 1e-7f);
    const float wg = w * gw;
    a0 += wg * f0;
    a1 += wg * f1;
    ag += wg * (d2 / s2);
}

// packed slots: NS=2 stride 4 vf4 (64B, 1 line): [m0 s0][f0 m1.xy][m1.z s1 f1]
//               NS=4 stride 8 vf4 (128B, 2 lines): g0,g1 in vf4 0-2; g2,g3 in 4-6
template<int NS>
__device__ __forceinline__ float2 splash_eval(
    int res, float cx, float cy, float cz,
    const vf4* __restrict__ slots, float& ag)
{
    int px, py, pz; float fx, fy, fz;
    corner_setup(res, cx, cy, cz, px, py, pz, fx, fy, fz);

    float a0 = 0.0f, a1 = 0.0f;
    ag = 0.0f;
#pragma unroll
    for (int k = 0; k < 8; ++k) {
        const int ox = (k >> 2) & 1, oy = (k >> 1) & 1, oz = k & 1;
        const int ix = px + ox, iy = py + oy, iz = pz + oz;
        const float w = (ox ? fx : 1.0f - fx) * (oy ? fy : 1.0f - fy) * (oz ? fz : 1.0f - fz);
        unsigned h = (unsigned)ix ^ ((unsigned)iy * 2654435761u) ^ ((unsigned)iz * 805459861u);
        const int idx = (int)(h & HMASK);
        const vf4* sp = slots + (size_t)idx * (NS == 2 ? 4 : 8);

        vf4 w0 = sp[0], w1 = sp[1], w2 = sp[2];
        gauss_term(w, cx, cy, cz, w0.x, w0.y, w0.z, w0.w, w1.x, w1.y, a0, a1, ag);
        gauss_term(w, cx, cy, cz, w1.z, w1.w, w2.x, w2.y, w2.z, w2.w, a0, a1, ag);
        if (NS == 4) {
            vf4 w4 = sp[4], w5 = sp[5], w6 = sp[6];
            gauss_term(w, cx, cy, cz, w4.x, w4.y, w4.z, w4.w, w5.x, w5.y, a0, a1, ag);
            gauss_term(w, cx, cy, cz, w5.z, w5.w, w6.x, w6.y, w6.z, w6.w, a0, a1, ag);
        }
    }
    return make_float2(a0, a1);
}

// fallback splash (direct table loads) if ws too small
template<int NS>
__device__ __forceinline__ float2 splash_direct(
    int res, int fbase, int gbase, float cx, float cy, float cz,
    const float* __restrict__ feats, const float* __restrict__ means,
    const float* __restrict__ stds, float& ag)
{
    int px, py, pz; float fx, fy, fz;
    corner_setup(res, cx, cy, cz, px, py, pz, fx, fy, fz);

    float a0 = 0.0f, a1 = 0.0f;
    ag = 0.0f;
#pragma unroll
    for (int k = 0; k < 8; ++k) {
        const int ox = (k >> 2) & 1, oy = (k >> 1) & 1, oz = k & 1;
        const int ix = px + ox, iy = py + oy, iz = pz + oz;
        const float w = (ox ? fx : 1.0f - fx) * (oy ? fy : 1.0f - fy) * (oz ? fz : 1.0f - fz);
        unsigned h = (unsigned)ix ^ ((unsigned)iy * 2654435761u) ^ ((unsigned)iz * 805459861u);
        const int idx = (int)(h & HMASK);
        const int grow = gbase + idx * NS;
        const float* m = means + (size_t)grow * 3;
        const float* s = stds + grow;
        const float* f = feats + (size_t)(fbase + idx * NS) * 2;
#pragma unroll
        for (int si = 0; si < NS; ++si)
            gauss_term(w, cx, cy, cz, m[3*si], m[3*si+1], m[3*si+2], s[si],
                       f[2*si], f[2*si+1], a0, a1, ag);
    }
    return make_float2(a0, a1);
}

// repack L14/L15 (means/stds/feats) into line-aligned AoS slots in ws
__global__ __launch_bounds__(256) void repack_kernel(
    const float* __restrict__ means, const float* __restrict__ stds,
    const float* __restrict__ feats, float* __restrict__ ws)
{
    const int i = blockIdx.x * 256 + threadIdx.x;     // 0 .. 262143
    if (i < 131072) {
        // level 14: ns=2, gbase=0, fbase=1491287
        const int grow = i * 2;
        const float* m = means + (size_t)grow * 3;
        const float* f = feats + (size_t)(1491287 + grow) * 2;
        const float s0 = stds[grow], s1 = stds[grow + 1];
        vf4* dst = (vf4*)ws + (size_t)i * 4;          // 64B slot, line-aligned
        dst[0] = (vf4){m[0], m[1], m[2], s0};
        dst[1] = (vf4){f[0], f[1], m[3], m[4]};
        dst[2] = (vf4){m[5], s1, f[2], f[3]};
    } else {
        // level 15: ns=4, gbase=262144, fbase=1753431
        const int j = i - 131072;
        const int grow = 262144 + j * 4;
        const float* m = means + (size_t)grow * 3;
        const float* s = stds + grow;
        const float* f = feats + (size_t)(1753431 + j * 4) * 2;
        vf4* dst = (vf4*)ws + 524288 + (size_t)j * 8; // 128B slot = 2 lines
        dst[0] = (vf4){m[0], m[1], m[2], s[0]};       // line 0: gauss 0,1
        dst[1] = (vf4){f[0], f[1], m[3], m[4]};
        dst[2] = (vf4){m[5], s[1], f[2], f[3]};
        dst[4] = (vf4){m[6], m[7], m[8], s[2]};       // line 1: gauss 2,3
        dst[5] = (vf4){f[4], f[5], m[9], m[10]};
        dst[6] = (vf4){m[11], s[3], f[6], f[7]};
    }
}

template<bool PACKED>
__global__ __launch_bounds__(256) void splash_enc(
    const float* __restrict__ coords, const float* __restrict__ feats,
    const float* __restrict__ means,  const float* __restrict__ stds,
    const float* __restrict__ ws, float* __restrict__ out, int N)
{
    const int n = blockIdx.x * 256 + threadIdx.x;
    if (n >= N) return;
    const float cx = coords[3*n+0], cy = coords[3*n+1], cz = coords[3*n+2];

    float2 acc[8];
    if (blockIdx.y == 0) {
        acc[0] = plain_eval<false>(16,       0, cx, cy, cz, feats);
        acc[1] = plain_eval<false>(23,    4096, cx, cy, cz, feats);
        acc[2] = plain_eval<false>(34,   16263, cx, cy, cz, feats);
        acc[3] = plain_eval<false>(50,   55567, cx, cy, cz, feats);
        acc[4] = plain_eval<true >(74,  180567, cx, cy, cz, feats);
        acc[5] = plain_eval<true >(109, 311639, cx, cy, cz, feats);
        acc[6] = plain_eval<true >(161, 442711, cx, cy, cz, feats);
        acc[7] = plain_eval<true >(237, 573783, cx, cy, cz, feats);
    } else {
        acc[0] = plain_eval<true>(348,   704855, cx, cy, cz, feats);
        acc[1] = plain_eval<true>(512,   835927, cx, cy, cz, feats);
        acc[2] = plain_eval<true>(753,   966999, cx, cy, cz, feats);
        acc[3] = plain_eval<true>(1108, 1098071, cx, cy, cz, feats);
        acc[4] = plain_eval<true>(1629, 1229143, cx, cy, cz, feats);
        acc[5] = plain_eval<true>(2394, 1360215, cx, cy, cz, feats);
        float g14, g15;
        if (PACKED) {
            acc[6] = splash_eval<2>(3520, cx, cy, cz, (const vf4*)ws,          g14);
            acc[7] = splash_eval<4>(5174, cx, cy, cz, (const vf4*)ws + 524288, g15);
        } else {
            acc[6] = splash_direct<2>(3520, 1491287, 0,      cx, cy, cz, feats, means, stds, g14);
            acc[7] = splash_direct<4>(5174, 1753431, 262144, cx, cy, cz, feats, means, stds, g15);
        }
        *(float2*)(out + (size_t)N * 32 + 2 * n) = make_float2(g14, g15);  // coalesced
    }

    // one full 64B line per thread -> no write amplification
    vf4* o = (vf4*)(out + (size_t)n * 32 + blockIdx.y * 16);
    o[0] = (vf4){acc[0].x, acc[0].y, acc[1].x, acc[1].y};
    o[1] = (vf4){acc[2].x, acc[2].y, acc[3].x, acc[3].y};
    o[2] = (vf4){acc[4].x, acc[4].y, acc[5].x, acc[5].y};
    o[3] = (vf4){acc[6].x, acc[6].y, acc[7].x, acc[7].y};
}

extern "C" void kernel_launch(void* const* d_in, const int* in_sizes, int n_in,
                              void* d_out, int out_size, void* d_ws, size_t ws_size,
                              hipStream_t stream) {
    const float* coords = (const float*)d_in[0];
    const float* feats  = (const float*)d_in[1];
    const float* means  = (const float*)d_in[2];
    const float* stds   = (const float*)d_in[3];
    float* out = (float*)d_out;
    const int N = in_sizes[0] / 3;   // 262144

    const bool packed = (ws_size >= 25165824);   // 8MB (L14) + 16MB (L15)
    dim3 grid((N + 255) / 256, 2);
    if (packed) {
        repack_kernel<<<1024, 256, 0, stream>>>(means, stds, feats, (float*)d_ws);
        splash_enc<true><<<grid, 256, 0, stream>>>(coords, feats, means, stds,
                                                   (const float*)d_ws, out, N);
    } else {
        splash_enc<false><<<grid, 256, 0, stream>>>(coords, feats, means, stds,
                                                    (const float*)d_ws, out, N);
    }
}

// Round 4
// 282.100 us; speedup vs baseline: 2.2969x; 1.0022x over previous
//
#include <hip/hip_runtime.h>
#include <math.h>

// SplashEncoding: 16-level hash grid, trilinear interp; levels 14/15 add
// Gaussian splash mixtures (ns=2/4) feeding both feature and GMM outputs.
//
// R4 vs R3 (200us main, FETCH 392MB dominated by L14/L15 splash tables):
//  - fp16-pack splash tables with PRECOMPUTED reciprocals:
//      per gaussian: (mean-0.5) fp16, 1/(2s^2+eps), 1/(sqrt(2pi)s+eps), 1/s^2, feats
//      L15 slot: 32 halfs = 64B = ONE cache line (was 2 lines)
//      L14 slot: 16 halfs = 32B -> 4MB table fits per-XCD L2
//    kills all divides in the hot loop; __expf for the rest
//  - one thread = one point, ALL 16 levels: perfect block balance (no y=0/y=1
//    tail), coords read once, two 64B full-line output writes
//  - error budget: threshold 0.205, fp16 offset-means -> predicted ~0.05

#define HMASK 131071
typedef float vf4 __attribute__((ext_vector_type(4)));
typedef _Float16 h8 __attribute__((ext_vector_type(8)));

__device__ __forceinline__ void corner_setup(int res, float cx, float cy, float cz,
                                             int& px, int& py, int& pz,
                                             float& fx, float& fy, float& fz)
{
    const float hi = (float)((double)res - 1.001);   // matches jnp.clip(res*c, 0, res-1.001)
    float x = fminf(fmaxf((float)res * cx, 0.0f), hi);
    float y = fminf(fmaxf((float)res * cy, 0.0f), hi);
    float z = fminf(fmaxf((float)res * cz, 0.0f), hi);
    px = (int)x; py = (int)y; pz = (int)z;           // >=0 so trunc == floor
    fx = x - (float)px; fy = y - (float)py; fz = z - (float)pz;
}

template<bool HASH>
__device__ __forceinline__ float2 plain_eval(
    int res, int fbase, float cx, float cy, float cz,
    const float* __restrict__ feats)
{
    int px, py, pz; float fx, fy, fz;
    corner_setup(res, cx, cy, cz, px, py, pz, fx, fy, fz);

    int   idxs[8];
    float ws[8];
#pragma unroll
    for (int k = 0; k < 8; ++k) {
        const int ox = (k >> 2) & 1, oy = (k >> 1) & 1, oz = k & 1;
        const int ix = px + ox, iy = py + oy, iz = pz + oz;
        ws[k] = (ox ? fx : 1.0f - fx) * (oy ? fy : 1.0f - fy) * (oz ? fz : 1.0f - fz);
        if (HASH) {
            unsigned h = (unsigned)ix ^ ((unsigned)iy * 2654435761u) ^ ((unsigned)iz * 805459861u);
            idxs[k] = (int)(h & HMASK);
        } else {
            idxs[k] = ix + iy * res + iz * res * res;
        }
    }
    float2 fv[8];      // batch the 8 gathers for memory-level parallelism
#pragma unroll
    for (int k = 0; k < 8; ++k)
        fv[k] = *(const float2*)(feats + (size_t)(fbase + idxs[k]) * 2);

    float a0 = 0.0f, a1 = 0.0f;
#pragma unroll
    for (int k = 0; k < 8; ++k) { a0 += ws[k] * fv[k].x; a1 += ws[k] * fv[k].y; }
    return make_float2(a0, a1);
}

__device__ __forceinline__ void gauss_pre(float w, float dx, float dy, float dz,
                                          float i2s, float inrm, float is2,
                                          float f0, float f1,
                                          float& a0, float& a1, float& ag)
{
    const float d2 = dx*dx + dy*dy + dz*dz;
    const float sq = d2 * i2s;
    const float gw = __expf(-sq) * inrm;
    const float wg = w * gw;
    a0 += wg * f0;
    a1 += wg * f1;
    ag += wg * (d2 * is2);
}

// L14 packed slot (32B = 2 h8):
//   A: mo0.xyz mo1.xyz i2s0 i2s1      B: inrm0 inrm1 is20 is21 f00 f01 f10 f11
__device__ __forceinline__ float2 splash14_packed(
    float cx, float cy, float cz, float cox, float coy, float coz,
    const h8* __restrict__ slots, float& ag)
{
    int px, py, pz; float fx, fy, fz;
    corner_setup(3520, cx, cy, cz, px, py, pz, fx, fy, fz);
    float a0 = 0.0f, a1 = 0.0f;
    ag = 0.0f;
#pragma unroll
    for (int k = 0; k < 8; ++k) {
        const int ox = (k >> 2) & 1, oy = (k >> 1) & 1, oz = k & 1;
        const int ix = px + ox, iy = py + oy, iz = pz + oz;
        const float w = (ox ? fx : 1.0f - fx) * (oy ? fy : 1.0f - fy) * (oz ? fz : 1.0f - fz);
        unsigned h = (unsigned)ix ^ ((unsigned)iy * 2654435761u) ^ ((unsigned)iz * 805459861u);
        const int idx = (int)(h & HMASK);
        const h8* sp = slots + (size_t)idx * 2;
        h8 A = sp[0], B = sp[1];
        gauss_pre(w, cox - (float)A[0], coy - (float)A[1], coz - (float)A[2],
                  (float)A[6], (float)B[0], (float)B[2], (float)B[4], (float)B[5], a0, a1, ag);
        gauss_pre(w, cox - (float)A[3], coy - (float)A[4], coz - (float)A[5],
                  (float)A[7], (float)B[1], (float)B[3], (float)B[6], (float)B[7], a0, a1, ag);
    }
    return make_float2(a0, a1);
}

// L15 packed slot (64B = 4 h8 = ONE cache line):
//   A: mo[0..7]   B: mo[8..11] i2s[0..3]   C: inrm[0..3] is2[0..3]   D: f[0..7]
__device__ __forceinline__ float2 splash15_packed(
    float cx, float cy, float cz, float cox, float coy, float coz,
    const h8* __restrict__ slots, float& ag)
{
    int px, py, pz; float fx, fy, fz;
    corner_setup(5174, cx, cy, cz, px, py, pz, fx, fy, fz);
    float a0 = 0.0f, a1 = 0.0f;
    ag = 0.0f;
#pragma unroll
    for (int k = 0; k < 8; ++k) {
        const int ox = (k >> 2) & 1, oy = (k >> 1) & 1, oz = k & 1;
        const int ix = px + ox, iy = py + oy, iz = pz + oz;
        const float w = (ox ? fx : 1.0f - fx) * (oy ? fy : 1.0f - fy) * (oz ? fz : 1.0f - fz);
        unsigned h = (unsigned)ix ^ ((unsigned)iy * 2654435761u) ^ ((unsigned)iz * 805459861u);
        const int idx = (int)(h & HMASK);
        const h8* sp = slots + (size_t)idx * 4;
        h8 A = sp[0], B = sp[1], C = sp[2], D = sp[3];
        gauss_pre(w, cox - (float)A[0], coy - (float)A[1], coz - (float)A[2],
                  (float)B[4], (float)C[0], (float)C[4], (float)D[0], (float)D[1], a0, a1, ag);
        gauss_pre(w, cox - (float)A[3], coy - (float)A[4], coz - (float)A[5],
                  (float)B[5], (float)C[1], (float)C[5], (float)D[2], (float)D[3], a0, a1, ag);
        gauss_pre(w, cox - (float)A[6], coy - (float)A[7], coz - (float)B[0],
                  (float)B[6], (float)C[2], (float)C[6], (float)D[4], (float)D[5], a0, a1, ag);
        gauss_pre(w, cox - (float)B[1], coy - (float)B[2], coz - (float)B[3],
                  (float)B[7], (float)C[3], (float)C[7], (float)D[6], (float)D[7], a0, a1, ag);
    }
    return make_float2(a0, a1);
}

// fallback splash (direct fp32 table loads) if ws too small
template<int NS>
__device__ __forceinline__ float2 splash_direct(
    int res, int fbase, int gbase, float cx, float cy, float cz,
    const float* __restrict__ feats, const float* __restrict__ means,
    const float* __restrict__ stds, float& ag)
{
    int px, py, pz; float fx, fy, fz;
    corner_setup(res, cx, cy, cz, px, py, pz, fx, fy, fz);
    float a0 = 0.0f, a1 = 0.0f;
    ag = 0.0f;
#pragma unroll
    for (int k = 0; k < 8; ++k) {
        const int ox = (k >> 2) & 1, oy = (k >> 1) & 1, oz = k & 1;
        const int ix = px + ox, iy = py + oy, iz = pz + oz;
        const float w = (ox ? fx : 1.0f - fx) * (oy ? fy : 1.0f - fy) * (oz ? fz : 1.0f - fz);
        unsigned h = (unsigned)ix ^ ((unsigned)iy * 2654435761u) ^ ((unsigned)iz * 805459861u);
        const int idx = (int)(h & HMASK);
        const int grow = gbase + idx * NS;
        const float* m = means + (size_t)grow * 3;
        const float* s = stds + grow;
        const float* f = feats + (size_t)(fbase + idx * NS) * 2;
#pragma unroll
        for (int si = 0; si < NS; ++si) {
            const float dx = cx - m[3*si], dy = cy - m[3*si+1], dz = cz - m[3*si+2];
            const float sva = fabsf(s[si]);
            const float d2 = dx*dx + dy*dy + dz*dz;
            const float s2 = sva * sva;
            const float sq = d2 / (2.0f * s2 + 1e-7f);
            const float gw = expf(-sq) / (2.5066282746310002f * sva + 1e-7f);
            const float wg = w * gw;
            a0 += wg * f[2*si];
            a1 += wg * f[2*si+1];
            ag += wg * (d2 / s2);
        }
    }
    return make_float2(a0, a1);
}

// repack L14/L15 into fp16 AoS slots with precomputed reciprocals
__global__ __launch_bounds__(256) void repack_kernel(
    const float* __restrict__ means, const float* __restrict__ stds,
    const float* __restrict__ feats, h8* __restrict__ ws)
{
    const int i = blockIdx.x * 256 + threadIdx.x;     // 0 .. 262143
    if (i < 131072) {
        // level 14: ns=2, gbase=0, fbase=1491287
        const int grow = i * 2;
        const float* m = means + (size_t)grow * 3;
        const float* f = feats + (size_t)(1491287 + grow) * 2;
        const float s0 = fabsf(stds[grow]), s1 = fabsf(stds[grow + 1]);
        h8 A, B;
        A[0] = (_Float16)(m[0] - 0.5f); A[1] = (_Float16)(m[1] - 0.5f); A[2] = (_Float16)(m[2] - 0.5f);
        A[3] = (_Float16)(m[3] - 0.5f); A[4] = (_Float16)(m[4] - 0.5f); A[5] = (_Float16)(m[5] - 0.5f);
        A[6] = (_Float16)(1.0f / (2.0f * s0 * s0 + 1e-7f));
        A[7] = (_Float16)(1.0f / (2.0f * s1 * s1 + 1e-7f));
        B[0] = (_Float16)(1.0f / (2.5066282746310002f * s0 + 1e-7f));
        B[1] = (_Float16)(1.0f / (2.5066282746310002f * s1 + 1e-7f));
        B[2] = (_Float16)(1.0f / (s0 * s0));
        B[3] = (_Float16)(1.0f / (s1 * s1));
        B[4] = (_Float16)f[0]; B[5] = (_Float16)f[1]; B[6] = (_Float16)f[2]; B[7] = (_Float16)f[3];
        h8* dst = ws + (size_t)i * 2;
        dst[0] = A; dst[1] = B;
    } else {
        // level 15: ns=4, gbase=262144, fbase=1753431
        const int j = i - 131072;
        const int grow = 262144 + j * 4;
        const float* m = means + (size_t)grow * 3;
        const float* s = stds + grow;
        const float* f = feats + (size_t)(1753431 + j * 4) * 2;
        h8 A, B, C, D;
#pragma unroll
        for (int t = 0; t < 8; ++t)  A[t] = (_Float16)(m[t] - 0.5f);
#pragma unroll
        for (int t = 0; t < 4; ++t)  B[t] = (_Float16)(m[8 + t] - 0.5f);
#pragma unroll
        for (int t = 0; t < 4; ++t) {
            const float sv = fabsf(s[t]);
            B[4 + t] = (_Float16)(1.0f / (2.0f * sv * sv + 1e-7f));
            C[t]     = (_Float16)(1.0f / (2.5066282746310002f * sv + 1e-7f));
            C[4 + t] = (_Float16)(1.0f / (sv * sv));
        }
#pragma unroll
        for (int t = 0; t < 8; ++t)  D[t] = (_Float16)f[t];
        h8* dst = ws + 262144 + (size_t)j * 4;   // after 4MB L14 region; 64B slot
        dst[0] = A; dst[1] = B; dst[2] = C; dst[3] = D;
    }
}

template<bool PACKED>
__global__ __launch_bounds__(256) void splash_enc(
    const float* __restrict__ coords, const float* __restrict__ feats,
    const float* __restrict__ means,  const float* __restrict__ stds,
    const h8* __restrict__ ws, float* __restrict__ out, int N)
{
    const int n = blockIdx.x * 256 + threadIdx.x;
    if (n >= N) return;
    const float cx = coords[3*n+0], cy = coords[3*n+1], cz = coords[3*n+2];
    const float cox = cx - 0.5f, coy = cy - 0.5f, coz = cz - 0.5f;
    vf4* o = (vf4*)(out + (size_t)n * 32);

    // phase A: levels 0-7 -> first 64B line
    {
        float2 acc[8];
        acc[0] = plain_eval<false>(16,       0, cx, cy, cz, feats);
        acc[1] = plain_eval<false>(23,    4096, cx, cy, cz, feats);
        acc[2] = plain_eval<false>(34,   16263, cx, cy, cz, feats);
        acc[3] = plain_eval<false>(50,   55567, cx, cy, cz, feats);
        acc[4] = plain_eval<true >(74,  180567, cx, cy, cz, feats);
        acc[5] = plain_eval<true >(109, 311639, cx, cy, cz, feats);
        acc[6] = plain_eval<true >(161, 442711, cx, cy, cz, feats);
        acc[7] = plain_eval<true >(237, 573783, cx, cy, cz, feats);
        o[0] = (vf4){acc[0].x, acc[0].y, acc[1].x, acc[1].y};
        o[1] = (vf4){acc[2].x, acc[2].y, acc[3].x, acc[3].y};
        o[2] = (vf4){acc[4].x, acc[4].y, acc[5].x, acc[5].y};
        o[3] = (vf4){acc[6].x, acc[6].y, acc[7].x, acc[7].y};
    }
    // phase B: levels 8-15 -> second 64B line (+ gmm pair)
    {
        float2 acc[8];
        acc[0] = plain_eval<true>(348,   704855, cx, cy, cz, feats);
        acc[1] = plain_eval<true>(512,   835927, cx, cy, cz, feats);
        acc[2] = plain_eval<true>(753,   966999, cx, cy, cz, feats);
        acc[3] = plain_eval<true>(1108, 1098071, cx, cy, cz, feats);
        acc[4] = plain_eval<true>(1629, 1229143, cx, cy, cz, feats);
        acc[5] = plain_eval<true>(2394, 1360215, cx, cy, cz, feats);
        float g14, g15;
        if (PACKED) {
            acc[6] = splash14_packed(cx, cy, cz, cox, coy, coz, ws, g14);
            acc[7] = splash15_packed(cx, cy, cz, cox, coy, coz, ws + 262144, g15);
        } else {
            acc[6] = splash_direct<2>(3520, 1491287, 0,      cx, cy, cz, feats, means, stds, g14);
            acc[7] = splash_direct<4>(5174, 1753431, 262144, cx, cy, cz, feats, means, stds, g15);
        }
        o[4] = (vf4){acc[0].x, acc[0].y, acc[1].x, acc[1].y};
        o[5] = (vf4){acc[2].x, acc[2].y, acc[3].x, acc[3].y};
        o[6] = (vf4){acc[4].x, acc[4].y, acc[5].x, acc[5].y};
        o[7] = (vf4){acc[6].x, acc[6].y, acc[7].x, acc[7].y};
        *(float2*)(out + (size_t)N * 32 + 2 * n) = make_float2(g14, g15);  // coalesced
    }
}

extern "C" void kernel_launch(void* const* d_in, const int* in_sizes, int n_in,
                              void* d_out, int out_size, void* d_ws, size_t ws_size,
                              hipStream_t stream) {
    const float* coords = (const float*)d_in[0];
    const float* feats  = (const float*)d_in[1];
    const float* means  = (const float*)d_in[2];
    const float* stds   = (const float*)d_in[3];
    float* out = (float*)d_out;
    const int N = in_sizes[0] / 3;   // 262144

    const bool packed = (ws_size >= 12582912);   // 4MB (L14) + 8MB (L15)
    dim3 grid((N + 255) / 256);
    if (packed) {
        repack_kernel<<<1024, 256, 0, stream>>>(means, stds, feats, (h8*)d_ws);
        splash_enc<true><<<grid, 256, 0, stream>>>(coords, feats, means, stds,
                                                   (const h8*)d_ws, out, N);
    } else {
        splash_enc<false><<<grid, 256, 0, stream>>>(coords, feats, means, stds,
                                                    (const h8*)d_ws, out, N);
    }
}

// Round 5
// 261.511 us; speedup vs baseline: 2.4778x; 1.0787x over previous
//
#include <hip/hip_runtime.h>
#include <math.h>

// SplashEncoding: 16-level hash grid, trilinear interp; levels 14/15 add
// Gaussian splash mixtures (ns=2/4) feeding both feature and GMM outputs.
//
// R5 vs R4 (205us, FETCH 452MB > R3's 392 despite halved tables):
//  R4 lesson: merging all levels into one thread DILUTED temporal reuse ->
//  L2 hit rate fell. Fix: three block populations dispatched in order
//  (near-sequential phases), each with a phase working set sized to L2:
//    pop0: levels 0-7   (~3.4MB tables -> resident)
//    pop1: levels 8-13 + L14 (~7MB -> mostly resident)
//    pop2: L15 only     (8MB, concentrated reuse)
//  Plus: fp16-pack plain levels 4-13 into ws (10MB -> 5MB footprint).
//  Keep R4's fp16 splash slots (L14 32B, L15 64B=1 line) + precomputed
//  reciprocals (no divides; __expf).

#define HMASK 131071
typedef float vf4 __attribute__((ext_vector_type(4)));
typedef _Float16 h8 __attribute__((ext_vector_type(8)));
typedef _Float16 h2 __attribute__((ext_vector_type(2)));

// fbases (float2 rows) of hashed plain levels 4..13
__constant__ int c_fbh[10] = {180567,311639,442711,573783,704855,835927,
                              966999,1098071,1229143,1360215};

__device__ __forceinline__ void corner_setup(int res, float cx, float cy, float cz,
                                             int& px, int& py, int& pz,
                                             float& fx, float& fy, float& fz)
{
    const float hi = (float)((double)res - 1.001);   // matches jnp.clip(res*c, 0, res-1.001)
    float x = fminf(fmaxf((float)res * cx, 0.0f), hi);
    float y = fminf(fmaxf((float)res * cy, 0.0f), hi);
    float z = fminf(fmaxf((float)res * cz, 0.0f), hi);
    px = (int)x; py = (int)y; pz = (int)z;           // >=0 so trunc == floor
    fx = x - (float)px; fy = y - (float)py; fz = z - (float)pz;
}

// fp32 plain level (levels 0-3 linear, or any level in fallback mode)
template<bool HASH>
__device__ __forceinline__ float2 plain_eval(
    int res, int fbase, float cx, float cy, float cz,
    const float* __restrict__ feats)
{
    int px, py, pz; float fx, fy, fz;
    corner_setup(res, cx, cy, cz, px, py, pz, fx, fy, fz);
    int   idxs[8];
    float ws[8];
#pragma unroll
    for (int k = 0; k < 8; ++k) {
        const int ox = (k >> 2) & 1, oy = (k >> 1) & 1, oz = k & 1;
        const int ix = px + ox, iy = py + oy, iz = pz + oz;
        ws[k] = (ox ? fx : 1.0f - fx) * (oy ? fy : 1.0f - fy) * (oz ? fz : 1.0f - fz);
        if (HASH) {
            unsigned h = (unsigned)ix ^ ((unsigned)iy * 2654435761u) ^ ((unsigned)iz * 805459861u);
            idxs[k] = (int)(h & HMASK);
        } else {
            idxs[k] = ix + iy * res + iz * res * res;
        }
    }
    float2 fv[8];
#pragma unroll
    for (int k = 0; k < 8; ++k)
        fv[k] = *(const float2*)(feats + (size_t)(fbase + idxs[k]) * 2);
    float a0 = 0.0f, a1 = 0.0f;
#pragma unroll
    for (int k = 0; k < 8; ++k) { a0 += ws[k] * fv[k].x; a1 += ws[k] * fv[k].y; }
    return make_float2(a0, a1);
}

// fp16 hashed plain level (4B/entry table in ws)
__device__ __forceinline__ float2 plain_eval_h(
    int res, const h2* __restrict__ tab, float cx, float cy, float cz)
{
    int px, py, pz; float fx, fy, fz;
    corner_setup(res, cx, cy, cz, px, py, pz, fx, fy, fz);
    int   idxs[8];
    float ws[8];
#pragma unroll
    for (int k = 0; k < 8; ++k) {
        const int ox = (k >> 2) & 1, oy = (k >> 1) & 1, oz = k & 1;
        const int ix = px + ox, iy = py + oy, iz = pz + oz;
        ws[k] = (ox ? fx : 1.0f - fx) * (oy ? fy : 1.0f - fy) * (oz ? fz : 1.0f - fz);
        unsigned h = (unsigned)ix ^ ((unsigned)iy * 2654435761u) ^ ((unsigned)iz * 805459861u);
        idxs[k] = (int)(h & HMASK);
    }
    h2 fv[8];
#pragma unroll
    for (int k = 0; k < 8; ++k) fv[k] = tab[idxs[k]];
    float a0 = 0.0f, a1 = 0.0f;
#pragma unroll
    for (int k = 0; k < 8; ++k) { a0 += ws[k] * (float)fv[k][0]; a1 += ws[k] * (float)fv[k][1]; }
    return make_float2(a0, a1);
}

__device__ __forceinline__ void gauss_pre(float w, float dx, float dy, float dz,
                                          float i2s, float inrm, float is2,
                                          float f0, float f1,
                                          float& a0, float& a1, float& ag)
{
    const float d2 = dx*dx + dy*dy + dz*dz;
    const float sq = d2 * i2s;
    const float gw = __expf(-sq) * inrm;
    const float wg = w * gw;
    a0 += wg * f0;
    a1 += wg * f1;
    ag += wg * (d2 * is2);
}

// L14 packed slot (32B = 2 h8):
//   A: mo0.xyz mo1.xyz i2s0 i2s1      B: inrm0 inrm1 is20 is21 f00 f01 f10 f11
__device__ __forceinline__ float2 splash14_packed(
    float cx, float cy, float cz, float cox, float coy, float coz,
    const h8* __restrict__ slots, float& ag)
{
    int px, py, pz; float fx, fy, fz;
    corner_setup(3520, cx, cy, cz, px, py, pz, fx, fy, fz);
    float a0 = 0.0f, a1 = 0.0f;
    ag = 0.0f;
#pragma unroll
    for (int k = 0; k < 8; ++k) {
        const int ox = (k >> 2) & 1, oy = (k >> 1) & 1, oz = k & 1;
        const int ix = px + ox, iy = py + oy, iz = pz + oz;
        const float w = (ox ? fx : 1.0f - fx) * (oy ? fy : 1.0f - fy) * (oz ? fz : 1.0f - fz);
        unsigned h = (unsigned)ix ^ ((unsigned)iy * 2654435761u) ^ ((unsigned)iz * 805459861u);
        const int idx = (int)(h & HMASK);
        const h8* sp = slots + (size_t)idx * 2;
        h8 A = sp[0], B = sp[1];
        gauss_pre(w, cox - (float)A[0], coy - (float)A[1], coz - (float)A[2],
                  (float)A[6], (float)B[0], (float)B[2], (float)B[4], (float)B[5], a0, a1, ag);
        gauss_pre(w, cox - (float)A[3], coy - (float)A[4], coz - (float)A[5],
                  (float)A[7], (float)B[1], (float)B[3], (float)B[6], (float)B[7], a0, a1, ag);
    }
    return make_float2(a0, a1);
}

// L15 packed slot (64B = 4 h8 = ONE cache line):
//   A: mo[0..7]   B: mo[8..11] i2s[0..3]   C: inrm[0..3] is2[0..3]   D: f[0..7]
__device__ __forceinline__ float2 splash15_packed(
    float cx, float cy, float cz, float cox, float coy, float coz,
    const h8* __restrict__ slots, float& ag)
{
    int px, py, pz; float fx, fy, fz;
    corner_setup(5174, cx, cy, cz, px, py, pz, fx, fy, fz);
    float a0 = 0.0f, a1 = 0.0f;
    ag = 0.0f;
#pragma unroll
    for (int k = 0; k < 8; ++k) {
        const int ox = (k >> 2) & 1, oy = (k >> 1) & 1, oz = k & 1;
        const int ix = px + ox, iy = py + oy, iz = pz + oz;
        const float w = (ox ? fx : 1.0f - fx) * (oy ? fy : 1.0f - fy) * (oz ? fz : 1.0f - fz);
        unsigned h = (unsigned)ix ^ ((unsigned)iy * 2654435761u) ^ ((unsigned)iz * 805459861u);
        const int idx = (int)(h & HMASK);
        const h8* sp = slots + (size_t)idx * 4;
        h8 A = sp[0], B = sp[1], C = sp[2], D = sp[3];
        gauss_pre(w, cox - (float)A[0], coy - (float)A[1], coz - (float)A[2],
                  (float)B[4], (float)C[0], (float)C[4], (float)D[0], (float)D[1], a0, a1, ag);
        gauss_pre(w, cox - (float)A[3], coy - (float)A[4], coz - (float)A[5],
                  (float)B[5], (float)C[1], (float)C[5], (float)D[2], (float)D[3], a0, a1, ag);
        gauss_pre(w, cox - (float)A[6], coy - (float)A[7], coz - (float)B[0],
                  (float)B[6], (float)C[2], (float)C[6], (float)D[4], (float)D[5], a0, a1, ag);
        gauss_pre(w, cox - (float)B[1], coy - (float)B[2], coz - (float)B[3],
                  (float)B[7], (float)C[3], (float)C[7], (float)D[6], (float)D[7], a0, a1, ag);
    }
    return make_float2(a0, a1);
}

// fallback splash (direct fp32 table loads) if ws too small
template<int NS>
__device__ __forceinline__ float2 splash_direct(
    int res, int fbase, int gbase, float cx, float cy, float cz,
    const float* __restrict__ feats, const float* __restrict__ means,
    const float* __restrict__ stds, float& ag)
{
    int px, py, pz; float fx, fy, fz;
    corner_setup(res, cx, cy, cz, px, py, pz, fx, fy, fz);
    float a0 = 0.0f, a1 = 0.0f;
    ag = 0.0f;
#pragma unroll
    for (int k = 0; k < 8; ++k) {
        const int ox = (k >> 2) & 1, oy = (k >> 1) & 1, oz = k & 1;
        const int ix = px + ox, iy = py + oy, iz = pz + oz;
        const float w = (ox ? fx : 1.0f - fx) * (oy ? fy : 1.0f - fy) * (oz ? fz : 1.0f - fz);
        unsigned h = (unsigned)ix ^ ((unsigned)iy * 2654435761u) ^ ((unsigned)iz * 805459861u);
        const int idx = (int)(h & HMASK);
        const int grow = gbase + idx * NS;
        const float* m = means + (size_t)grow * 3;
        const float* s = stds + grow;
        const float* f = feats + (size_t)(fbase + idx * NS) * 2;
#pragma unroll
        for (int si = 0; si < NS; ++si) {
            const float dx = cx - m[3*si], dy = cy - m[3*si+1], dz = cz - m[3*si+2];
            const float sva = fabsf(s[si]);
            const float d2 = dx*dx + dy*dy + dz*dz;
            const float s2 = sva * sva;
            const float sq = d2 / (2.0f * s2 + 1e-7f);
            const float gw = expf(-sq) / (2.5066282746310002f * sva + 1e-7f);
            const float wg = w * gw;
            a0 += wg * f[2*si];
            a1 += wg * f[2*si+1];
            ag += wg * (d2 / s2);
        }
    }
    return make_float2(a0, a1);
}

// ws layout (in halfs):
//   [0, 2621440)            : levels 4-13 fp16 feat tables, 262144 halfs each
//   [2621440, 4718592)      : L14 slots (16 halfs each)
//   [4718592, 8912896)      : L15 slots (32 halfs each)
__global__ __launch_bounds__(256) void repack_kernel(
    const float* __restrict__ means, const float* __restrict__ stds,
    const float* __restrict__ feats, _Float16* __restrict__ ws)
{
    const int i = blockIdx.x * 256 + threadIdx.x;     // 0 .. 1572863
    if (i < 1310720) {
        // plain hashed levels 4-13: fp16 feats
        const int lvl = i >> 17;            // /131072
        const int e   = i & 131071;
        const float2 f = *(const float2*)(feats + (size_t)(c_fbh[lvl] + e) * 2);
        h2 v; v[0] = (_Float16)f.x; v[1] = (_Float16)f.y;
        ((h2*)ws)[lvl * 131072 + e] = v;
    } else if (i < 1441792) {
        // level 14: ns=2, gbase=0, fbase=1491287
        const int e = i - 1310720;
        const int grow = e * 2;
        const float* m = means + (size_t)grow * 3;
        const float* f = feats + (size_t)(1491287 + grow) * 2;
        const float s0 = fabsf(stds[grow]), s1 = fabsf(stds[grow + 1]);
        h8 A, B;
        A[0] = (_Float16)(m[0] - 0.5f); A[1] = (_Float16)(m[1] - 0.5f); A[2] = (_Float16)(m[2] - 0.5f);
        A[3] = (_Float16)(m[3] - 0.5f); A[4] = (_Float16)(m[4] - 0.5f); A[5] = (_Float16)(m[5] - 0.5f);
        A[6] = (_Float16)(1.0f / (2.0f * s0 * s0 + 1e-7f));
        A[7] = (_Float16)(1.0f / (2.0f * s1 * s1 + 1e-7f));
        B[0] = (_Float16)(1.0f / (2.5066282746310002f * s0 + 1e-7f));
        B[1] = (_Float16)(1.0f / (2.5066282746310002f * s1 + 1e-7f));
        B[2] = (_Float16)(1.0f / (s0 * s0));
        B[3] = (_Float16)(1.0f / (s1 * s1));
        B[4] = (_Float16)f[0]; B[5] = (_Float16)f[1]; B[6] = (_Float16)f[2]; B[7] = (_Float16)f[3];
        h8* dst = (h8*)(ws + 2621440) + (size_t)e * 2;
        dst[0] = A; dst[1] = B;
    } else {
        // level 15: ns=4, gbase=262144, fbase=1753431
        const int e = i - 1441792;
        const int grow = 262144 + e * 4;
        const float* m = means + (size_t)grow * 3;
        const float* s = stds + grow;
        const float* f = feats + (size_t)(1753431 + e * 4) * 2;
        h8 A, B, C, D;
#pragma unroll
        for (int t = 0; t < 8; ++t)  A[t] = (_Float16)(m[t] - 0.5f);
#pragma unroll
        for (int t = 0; t < 4; ++t)  B[t] = (_Float16)(m[8 + t] - 0.5f);
#pragma unroll
        for (int t = 0; t < 4; ++t) {
            const float sv = fabsf(s[t]);
            B[4 + t] = (_Float16)(1.0f / (2.0f * sv * sv + 1e-7f));
            C[t]     = (_Float16)(1.0f / (2.5066282746310002f * sv + 1e-7f));
            C[4 + t] = (_Float16)(1.0f / (sv * sv));
        }
#pragma unroll
        for (int t = 0; t < 8; ++t)  D[t] = (_Float16)f[t];
        h8* dst = (h8*)(ws + 4718592) + (size_t)e * 4;
        dst[0] = A; dst[1] = B; dst[2] = C; dst[3] = D;
    }
}

template<bool PACKED>
__global__ __launch_bounds__(256) void splash_enc(
    const float* __restrict__ coords, const float* __restrict__ feats,
    const float* __restrict__ means,  const float* __restrict__ stds,
    const _Float16* __restrict__ ws, float* __restrict__ out, int N)
{
    const int n = blockIdx.x * 256 + threadIdx.x;
    if (n >= N) return;
    const float cx = coords[3*n+0], cy = coords[3*n+1], cz = coords[3*n+2];
    vf4* o = (vf4*)(out + (size_t)n * 32);
    const h2* tabs = (const h2*)ws;   // level L in [4,13]: tabs + (L-4)*131072

    if (blockIdx.y == 0) {
        // ---- pop0: levels 0-7 (tables ~3.4MB -> L2-resident phase)
        float2 acc[8];
        acc[0] = plain_eval<false>(16,       0, cx, cy, cz, feats);
        acc[1] = plain_eval<false>(23,    4096, cx, cy, cz, feats);
        acc[2] = plain_eval<false>(34,   16263, cx, cy, cz, feats);
        acc[3] = plain_eval<false>(50,   55567, cx, cy, cz, feats);
        if (PACKED) {
            acc[4] = plain_eval_h(74,  tabs + 0 * 131072, cx, cy, cz);
            acc[5] = plain_eval_h(109, tabs + 1 * 131072, cx, cy, cz);
            acc[6] = plain_eval_h(161, tabs + 2 * 131072, cx, cy, cz);
            acc[7] = plain_eval_h(237, tabs + 3 * 131072, cx, cy, cz);
        } else {
            acc[4] = plain_eval<true>(74,  180567, cx, cy, cz, feats);
            acc[5] = plain_eval<true>(109, 311639, cx, cy, cz, feats);
            acc[6] = plain_eval<true>(161, 442711, cx, cy, cz, feats);
            acc[7] = plain_eval<true>(237, 573783, cx, cy, cz, feats);
        }
        o[0] = (vf4){acc[0].x, acc[0].y, acc[1].x, acc[1].y};
        o[1] = (vf4){acc[2].x, acc[2].y, acc[3].x, acc[3].y};
        o[2] = (vf4){acc[4].x, acc[4].y, acc[5].x, acc[5].y};
        o[3] = (vf4){acc[6].x, acc[6].y, acc[7].x, acc[7].y};
    } else if (blockIdx.y == 1) {
        // ---- pop1: levels 8-13 + L14 (~7MB phase working set)
        float2 acc[7];
        float g14;
        if (PACKED) {
            acc[0] = plain_eval_h(348,  tabs + 4 * 131072, cx, cy, cz);
            acc[1] = plain_eval_h(512,  tabs + 5 * 131072, cx, cy, cz);
            acc[2] = plain_eval_h(753,  tabs + 6 * 131072, cx, cy, cz);
            acc[3] = plain_eval_h(1108, tabs + 7 * 131072, cx, cy, cz);
            acc[4] = plain_eval_h(1629, tabs + 8 * 131072, cx, cy, cz);
            acc[5] = plain_eval_h(2394, tabs + 9 * 131072, cx, cy, cz);
            acc[6] = splash14_packed(cx, cy, cz, cx - 0.5f, cy - 0.5f, cz - 0.5f,
                                     (const h8*)(ws + 2621440), g14);
        } else {
            acc[0] = plain_eval<true>(348,   704855, cx, cy, cz, feats);
            acc[1] = plain_eval<true>(512,   835927, cx, cy, cz, feats);
            acc[2] = plain_eval<true>(753,   966999, cx, cy, cz, feats);
            acc[3] = plain_eval<true>(1108, 1098071, cx, cy, cz, feats);
            acc[4] = plain_eval<true>(1629, 1229143, cx, cy, cz, feats);
            acc[5] = plain_eval<true>(2394, 1360215, cx, cy, cz, feats);
            acc[6] = splash_direct<2>(3520, 1491287, 0, cx, cy, cz, feats, means, stds, g14);
        }
        o[4] = (vf4){acc[0].x, acc[0].y, acc[1].x, acc[1].y};
        o[5] = (vf4){acc[2].x, acc[2].y, acc[3].x, acc[3].y};
        o[6] = (vf4){acc[4].x, acc[4].y, acc[5].x, acc[5].y};
        *(float2*)(out + (size_t)n * 32 + 28) = make_float2(acc[6].x, acc[6].y);
        out[(size_t)N * 32 + 2 * n] = g14;
    } else {
        // ---- pop2: L15 only (8MB table, concentrated reuse)
        float g15;
        float2 a;
        if (PACKED) {
            a = splash15_packed(cx, cy, cz, cx - 0.5f, cy - 0.5f, cz - 0.5f,
                                (const h8*)(ws + 4718592), g15);
        } else {
            a = splash_direct<4>(5174, 1753431, 262144, cx, cy, cz, feats, means, stds, g15);
        }
        *(float2*)(out + (size_t)n * 32 + 30) = a;
        out[(size_t)N * 32 + 2 * n + 1] = g15;
    }
}

extern "C" void kernel_launch(void* const* d_in, const int* in_sizes, int n_in,
                              void* d_out, int out_size, void* d_ws, size_t ws_size,
                              hipStream_t stream) {
    const float* coords = (const float*)d_in[0];
    const float* feats  = (const float*)d_in[1];
    const float* means  = (const float*)d_in[2];
    const float* stds   = (const float*)d_in[3];
    float* out = (float*)d_out;
    const int N = in_sizes[0] / 3;   // 262144

    const bool packed = (ws_size >= 17825792);   // 5MB plain + 4MB L14 + 8MB L15
    dim3 grid((N + 255) / 256, 3);
    if (packed) {
        repack_kernel<<<6144, 256, 0, stream>>>(means, stds, feats, (_Float16*)d_ws);
        splash_enc<true><<<grid, 256, 0, stream>>>(coords, feats, means, stds,
                                                   (const _Float16*)d_ws, out, N);
    } else {
        splash_enc<false><<<grid, 256, 0, stream>>>(coords, feats, means, stds,
                                                    (const _Float16*)d_ws, out, N);
    }
}

// Round 6
// 239.532 us; speedup vs baseline: 2.7051x; 1.0918x over previous
//
#include <hip/hip_runtime.h>
#include <math.h>

// SplashEncoding: 16-level hash grid, trilinear interp; levels 14/15 add
// Gaussian splash mixtures (ns=2/4) feeding both feature and GMM outputs.
//
// R6 vs R5 (179us main; latency-bound, splash chains too serial):
//  - split splash across threads: L14 2 thr/pt (4 corners each), L15 4 thr/pt
//    (2 corners each); combine via __shfl_xor; 2-4x outstanding misses during
//    the dominant phases (occupancy 68% -> expect ~85%+)
//  - 1D grid in dispatch order [pop0 | pop1 lv8-13 | L14 | L15] keeps R5's
//    phase/cache separation (that separation was the R5 win; do not merge)
//  - vectorized repack loads (float4/float2)
//  - keep: fp16 plain tables (lv4-13) in ws, fp16 splash slots with
//    precomputed reciprocals (L14 32B, L15 64B = 1 line), __expf, no divides

#define HMASK 131071
typedef float vf4 __attribute__((ext_vector_type(4)));
typedef _Float16 h8 __attribute__((ext_vector_type(8)));
typedef _Float16 h2 __attribute__((ext_vector_type(2)));

// fbases (float2 rows) of hashed plain levels 4..13
__constant__ int c_fbh[10] = {180567,311639,442711,573783,704855,835927,
                              966999,1098071,1229143,1360215};

__device__ __forceinline__ void corner_setup(int res, float cx, float cy, float cz,
                                             int& px, int& py, int& pz,
                                             float& fx, float& fy, float& fz)
{
    const float hi = (float)((double)res - 1.001);   // matches jnp.clip(res*c, 0, res-1.001)
    float x = fminf(fmaxf((float)res * cx, 0.0f), hi);
    float y = fminf(fmaxf((float)res * cy, 0.0f), hi);
    float z = fminf(fmaxf((float)res * cz, 0.0f), hi);
    px = (int)x; py = (int)y; pz = (int)z;           // >=0 so trunc == floor
    fx = x - (float)px; fy = y - (float)py; fz = z - (float)pz;
}

// fp32 plain level (levels 0-3 linear, or fallback hashed)
template<bool HASH>
__device__ __forceinline__ float2 plain_eval(
    int res, int fbase, float cx, float cy, float cz,
    const float* __restrict__ feats)
{
    int px, py, pz; float fx, fy, fz;
    corner_setup(res, cx, cy, cz, px, py, pz, fx, fy, fz);
    int   idxs[8];
    float ws[8];
#pragma unroll
    for (int k = 0; k < 8; ++k) {
        const int ox = (k >> 2) & 1, oy = (k >> 1) & 1, oz = k & 1;
        const int ix = px + ox, iy = py + oy, iz = pz + oz;
        ws[k] = (ox ? fx : 1.0f - fx) * (oy ? fy : 1.0f - fy) * (oz ? fz : 1.0f - fz);
        if (HASH) {
            unsigned h = (unsigned)ix ^ ((unsigned)iy * 2654435761u) ^ ((unsigned)iz * 805459861u);
            idxs[k] = (int)(h & HMASK);
        } else {
            idxs[k] = ix + iy * res + iz * res * res;
        }
    }
    float2 fv[8];
#pragma unroll
    for (int k = 0; k < 8; ++k)
        fv[k] = *(const float2*)(feats + (size_t)(fbase + idxs[k]) * 2);
    float a0 = 0.0f, a1 = 0.0f;
#pragma unroll
    for (int k = 0; k < 8; ++k) { a0 += ws[k] * fv[k].x; a1 += ws[k] * fv[k].y; }
    return make_float2(a0, a1);
}

// fp16 hashed plain level (4B/entry table in ws)
__device__ __forceinline__ float2 plain_eval_h(
    int res, const h2* __restrict__ tab, float cx, float cy, float cz)
{
    int px, py, pz; float fx, fy, fz;
    corner_setup(res, cx, cy, cz, px, py, pz, fx, fy, fz);
    int   idxs[8];
    float ws[8];
#pragma unroll
    for (int k = 0; k < 8; ++k) {
        const int ox = (k >> 2) & 1, oy = (k >> 1) & 1, oz = k & 1;
        const int ix = px + ox, iy = py + oy, iz = pz + oz;
        ws[k] = (ox ? fx : 1.0f - fx) * (oy ? fy : 1.0f - fy) * (oz ? fz : 1.0f - fz);
        unsigned h = (unsigned)ix ^ ((unsigned)iy * 2654435761u) ^ ((unsigned)iz * 805459861u);
        idxs[k] = (int)(h & HMASK);
    }
    h2 fv[8];
#pragma unroll
    for (int k = 0; k < 8; ++k) fv[k] = tab[idxs[k]];
    float a0 = 0.0f, a1 = 0.0f;
#pragma unroll
    for (int k = 0; k < 8; ++k) { a0 += ws[k] * (float)fv[k][0]; a1 += ws[k] * (float)fv[k][1]; }
    return make_float2(a0, a1);
}

__device__ __forceinline__ void gauss_pre(float w, float dx, float dy, float dz,
                                          float i2s, float inrm, float is2,
                                          float f0, float f1,
                                          float& a0, float& a1, float& ag)
{
    const float d2 = dx*dx + dy*dy + dz*dz;
    const float sq = d2 * i2s;
    const float gw = __expf(-sq) * inrm;
    const float wg = w * gw;
    a0 += wg * f0;
    a1 += wg * f1;
    ag += wg * (d2 * is2);
}

// L14 packed slot (32B = 2 h8):
//   A: mo0.xyz mo1.xyz i2s0 i2s1      B: inrm0 inrm1 is20 is21 f00 f01 f10 f11
// partial: corners [k0, k0+4)
__device__ __forceinline__ void splash14_part(
    int k0, float cx, float cy, float cz, float cox, float coy, float coz,
    const h8* __restrict__ slots, float& a0, float& a1, float& ag)
{
    int px, py, pz; float fx, fy, fz;
    corner_setup(3520, cx, cy, cz, px, py, pz, fx, fy, fz);
    a0 = 0.0f; a1 = 0.0f; ag = 0.0f;
#pragma unroll
    for (int kk = 0; kk < 4; ++kk) {
        const int k = k0 + kk;
        const int ox = (k >> 2) & 1, oy = (k >> 1) & 1, oz = k & 1;
        const int ix = px + ox, iy = py + oy, iz = pz + oz;
        const float w = (ox ? fx : 1.0f - fx) * (oy ? fy : 1.0f - fy) * (oz ? fz : 1.0f - fz);
        unsigned h = (unsigned)ix ^ ((unsigned)iy * 2654435761u) ^ ((unsigned)iz * 805459861u);
        const int idx = (int)(h & HMASK);
        const h8* sp = slots + (size_t)idx * 2;
        h8 A = sp[0], B = sp[1];
        gauss_pre(w, cox - (float)A[0], coy - (float)A[1], coz - (float)A[2],
                  (float)A[6], (float)B[0], (float)B[2], (float)B[4], (float)B[5], a0, a1, ag);
        gauss_pre(w, cox - (float)A[3], coy - (float)A[4], coz - (float)A[5],
                  (float)A[7], (float)B[1], (float)B[3], (float)B[6], (float)B[7], a0, a1, ag);
    }
}

// L15 packed slot (64B = 4 h8 = ONE cache line):
//   A: mo[0..7]   B: mo[8..11] i2s[0..3]   C: inrm[0..3] is2[0..3]   D: f[0..7]
// partial: corners [k0, k0+2)
__device__ __forceinline__ void splash15_part(
    int k0, float cx, float cy, float cz, float cox, float coy, float coz,
    const h8* __restrict__ slots, float& a0, float& a1, float& ag)
{
    int px, py, pz; float fx, fy, fz;
    corner_setup(5174, cx, cy, cz, px, py, pz, fx, fy, fz);
    a0 = 0.0f; a1 = 0.0f; ag = 0.0f;
#pragma unroll
    for (int kk = 0; kk < 2; ++kk) {
        const int k = k0 + kk;
        const int ox = (k >> 2) & 1, oy = (k >> 1) & 1, oz = k & 1;
        const int ix = px + ox, iy = py + oy, iz = pz + oz;
        const float w = (ox ? fx : 1.0f - fx) * (oy ? fy : 1.0f - fy) * (oz ? fz : 1.0f - fz);
        unsigned h = (unsigned)ix ^ ((unsigned)iy * 2654435761u) ^ ((unsigned)iz * 805459861u);
        const int idx = (int)(h & HMASK);
        const h8* sp = slots + (size_t)idx * 4;
        h8 A = sp[0], B = sp[1], C = sp[2], D = sp[3];
        gauss_pre(w, cox - (float)A[0], coy - (float)A[1], coz - (float)A[2],
                  (float)B[4], (float)C[0], (float)C[4], (float)D[0], (float)D[1], a0, a1, ag);
        gauss_pre(w, cox - (float)A[3], coy - (float)A[4], coz - (float)A[5],
                  (float)B[5], (float)C[1], (float)C[5], (float)D[2], (float)D[3], a0, a1, ag);
        gauss_pre(w, cox - (float)A[6], coy - (float)A[7], coz - (float)B[0],
                  (float)B[6], (float)C[2], (float)C[6], (float)D[4], (float)D[5], a0, a1, ag);
        gauss_pre(w, cox - (float)B[1], coy - (float)B[2], coz - (float)B[3],
                  (float)B[7], (float)C[3], (float)C[7], (float)D[6], (float)D[7], a0, a1, ag);
    }
}

// fallback splash (direct fp32 table loads), corner range [k0, k0+kn)
template<int NS, int KN>
__device__ __forceinline__ void splash_direct_part(
    int k0, int res, int fbase, int gbase, float cx, float cy, float cz,
    const float* __restrict__ feats, const float* __restrict__ means,
    const float* __restrict__ stds, float& a0, float& a1, float& ag)
{
    int px, py, pz; float fx, fy, fz;
    corner_setup(res, cx, cy, cz, px, py, pz, fx, fy, fz);
    a0 = 0.0f; a1 = 0.0f; ag = 0.0f;
#pragma unroll
    for (int kk = 0; kk < KN; ++kk) {
        const int k = k0 + kk;
        const int ox = (k >> 2) & 1, oy = (k >> 1) & 1, oz = k & 1;
        const int ix = px + ox, iy = py + oy, iz = pz + oz;
        const float w = (ox ? fx : 1.0f - fx) * (oy ? fy : 1.0f - fy) * (oz ? fz : 1.0f - fz);
        unsigned h = (unsigned)ix ^ ((unsigned)iy * 2654435761u) ^ ((unsigned)iz * 805459861u);
        const int idx = (int)(h & HMASK);
        const int grow = gbase + idx * NS;
        const float* m = means + (size_t)grow * 3;
        const float* s = stds + grow;
        const float* f = feats + (size_t)(fbase + idx * NS) * 2;
#pragma unroll
        for (int si = 0; si < NS; ++si) {
            const float dx = cx - m[3*si], dy = cy - m[3*si+1], dz = cz - m[3*si+2];
            const float sva = fabsf(s[si]);
            const float d2 = dx*dx + dy*dy + dz*dz;
            const float s2 = sva * sva;
            const float sq = d2 / (2.0f * s2 + 1e-7f);
            const float gw = expf(-sq) / (2.5066282746310002f * sva + 1e-7f);
            const float wg = w * gw;
            a0 += wg * f[2*si];
            a1 += wg * f[2*si+1];
            ag += wg * (d2 / s2);
        }
    }
}

// ws layout (in halfs):
//   [0, 2621440)        : levels 4-13 fp16 feat tables, 262144 halfs each
//   [2621440, 4718592)  : L14 slots (16 halfs each)
//   [4718592, 8912896)  : L15 slots (32 halfs each)
__global__ __launch_bounds__(256) void repack_kernel(
    const float* __restrict__ means, const float* __restrict__ stds,
    const float* __restrict__ feats, _Float16* __restrict__ ws)
{
    const int i = blockIdx.x * 256 + threadIdx.x;     // 0 .. 1572863
    if (i < 1310720) {
        // plain hashed levels 4-13: fp16 feats
        const int lvl = i >> 17;            // /131072
        const int e   = i & 131071;
        const float2 f = *(const float2*)(feats + (size_t)(c_fbh[lvl] + e) * 2);
        h2 v; v[0] = (_Float16)f.x; v[1] = (_Float16)f.y;
        ((h2*)ws)[lvl * 131072 + e] = v;
    } else if (i < 1441792) {
        // level 14: ns=2, gbase=0, fbase=1491287
        const int e = i - 1310720;
        const float2* m2 = (const float2*)(means + (size_t)e * 6);       // 8B-aligned
        const float2 ma = m2[0], mb = m2[1], mc = m2[2];
        const float2 sv = *(const float2*)(stds + 2 * e);
        const float2* f2 = (const float2*)(feats + (size_t)(1491287 + 2 * e) * 2);
        const float2 fa = f2[0], fb = f2[1];
        const float s0 = fabsf(sv.x), s1 = fabsf(sv.y);
        h8 A, B;
        A[0] = (_Float16)(ma.x - 0.5f); A[1] = (_Float16)(ma.y - 0.5f); A[2] = (_Float16)(mb.x - 0.5f);
        A[3] = (_Float16)(mb.y - 0.5f); A[4] = (_Float16)(mc.x - 0.5f); A[5] = (_Float16)(mc.y - 0.5f);
        A[6] = (_Float16)(1.0f / (2.0f * s0 * s0 + 1e-7f));
        A[7] = (_Float16)(1.0f / (2.0f * s1 * s1 + 1e-7f));
        B[0] = (_Float16)(1.0f / (2.5066282746310002f * s0 + 1e-7f));
        B[1] = (_Float16)(1.0f / (2.5066282746310002f * s1 + 1e-7f));
        B[2] = (_Float16)(1.0f / (s0 * s0));
        B[3] = (_Float16)(1.0f / (s1 * s1));
        B[4] = (_Float16)fa.x; B[5] = (_Float16)fa.y; B[6] = (_Float16)fb.x; B[7] = (_Float16)fb.y;
        h8* dst = (h8*)(ws + 2621440) + (size_t)e * 2;
        dst[0] = A; dst[1] = B;
    } else {
        // level 15: ns=4, gbase=262144, fbase=1753431
        const int e = i - 1441792;
        const vf4* m4 = (const vf4*)(means + (size_t)(262144 + 4 * e) * 3); // 16B-aligned
        const vf4 u = m4[0], v = m4[1], w = m4[2];
        const vf4 s4 = *(const vf4*)(stds + 262144 + 4 * e);                // 16B-aligned
        const float2* f2 = (const float2*)(feats + (size_t)(1753431 + 4 * e) * 2);
        const float2 fa = f2[0], fb = f2[1], fc = f2[2], fd = f2[3];
        h8 A, B, C, D;
        A[0] = (_Float16)(u.x - 0.5f); A[1] = (_Float16)(u.y - 0.5f); A[2] = (_Float16)(u.z - 0.5f);
        A[3] = (_Float16)(u.w - 0.5f); A[4] = (_Float16)(v.x - 0.5f); A[5] = (_Float16)(v.y - 0.5f);
        A[6] = (_Float16)(v.z - 0.5f); A[7] = (_Float16)(v.w - 0.5f);
        B[0] = (_Float16)(w.x - 0.5f); B[1] = (_Float16)(w.y - 0.5f);
        B[2] = (_Float16)(w.z - 0.5f); B[3] = (_Float16)(w.w - 0.5f);
        const float sv[4] = {fabsf(s4.x), fabsf(s4.y), fabsf(s4.z), fabsf(s4.w)};
#pragma unroll
        for (int t = 0; t < 4; ++t) {
            B[4 + t] = (_Float16)(1.0f / (2.0f * sv[t] * sv[t] + 1e-7f));
            C[t]     = (_Float16)(1.0f / (2.5066282746310002f * sv[t] + 1e-7f));
            C[4 + t] = (_Float16)(1.0f / (sv[t] * sv[t]));
        }
        D[0] = (_Float16)fa.x; D[1] = (_Float16)fa.y; D[2] = (_Float16)fb.x; D[3] = (_Float16)fb.y;
        D[4] = (_Float16)fc.x; D[5] = (_Float16)fc.y; D[6] = (_Float16)fd.x; D[7] = (_Float16)fd.y;
        h8* dst = (h8*)(ws + 4718592) + (size_t)e * 4;
        dst[0] = A; dst[1] = B; dst[2] = C; dst[3] = D;
    }
}

// grid: [0,1024) pop0 lv0-7 | [1024,2048) pop1 lv8-13 |
//       [2048,4096) L14 2thr/pt | [4096,8192) L15 4thr/pt
template<bool PACKED>
__global__ __launch_bounds__(256) void splash_enc(
    const float* __restrict__ coords, const float* __restrict__ feats,
    const float* __restrict__ means,  const float* __restrict__ stds,
    const _Float16* __restrict__ ws, float* __restrict__ out, int N)
{
    const int b = blockIdx.x;
    const int tid = threadIdx.x;
    const h2* tabs = (const h2*)ws;   // level L in [4,13]: tabs + (L-4)*131072
    float* gmm = out + (size_t)N * 32;

    if (b < 1024) {
        // ---- pop0: levels 0-7 (~3.4MB tables -> L2-resident phase)
        const int n = b * 256 + tid;
        const float cx = coords[3*n+0], cy = coords[3*n+1], cz = coords[3*n+2];
        float2 acc[8];
        acc[0] = plain_eval<false>(16,       0, cx, cy, cz, feats);
        acc[1] = plain_eval<false>(23,    4096, cx, cy, cz, feats);
        acc[2] = plain_eval<false>(34,   16263, cx, cy, cz, feats);
        acc[3] = plain_eval<false>(50,   55567, cx, cy, cz, feats);
        if (PACKED) {
            acc[4] = plain_eval_h(74,  tabs + 0 * 131072, cx, cy, cz);
            acc[5] = plain_eval_h(109, tabs + 1 * 131072, cx, cy, cz);
            acc[6] = plain_eval_h(161, tabs + 2 * 131072, cx, cy, cz);
            acc[7] = plain_eval_h(237, tabs + 3 * 131072, cx, cy, cz);
        } else {
            acc[4] = plain_eval<true>(74,  180567, cx, cy, cz, feats);
            acc[5] = plain_eval<true>(109, 311639, cx, cy, cz, feats);
            acc[6] = plain_eval<true>(161, 442711, cx, cy, cz, feats);
            acc[7] = plain_eval<true>(237, 573783, cx, cy, cz, feats);
        }
        vf4* o = (vf4*)(out + (size_t)n * 32);
        o[0] = (vf4){acc[0].x, acc[0].y, acc[1].x, acc[1].y};
        o[1] = (vf4){acc[2].x, acc[2].y, acc[3].x, acc[3].y};
        o[2] = (vf4){acc[4].x, acc[4].y, acc[5].x, acc[5].y};
        o[3] = (vf4){acc[6].x, acc[6].y, acc[7].x, acc[7].y};
    } else if (b < 2048) {
        // ---- pop1: levels 8-13 (3MB fp16 tables)
        const int n = (b - 1024) * 256 + tid;
        const float cx = coords[3*n+0], cy = coords[3*n+1], cz = coords[3*n+2];
        float2 acc[6];
        if (PACKED) {
            acc[0] = plain_eval_h(348,  tabs + 4 * 131072, cx, cy, cz);
            acc[1] = plain_eval_h(512,  tabs + 5 * 131072, cx, cy, cz);
            acc[2] = plain_eval_h(753,  tabs + 6 * 131072, cx, cy, cz);
            acc[3] = plain_eval_h(1108, tabs + 7 * 131072, cx, cy, cz);
            acc[4] = plain_eval_h(1629, tabs + 8 * 131072, cx, cy, cz);
            acc[5] = plain_eval_h(2394, tabs + 9 * 131072, cx, cy, cz);
        } else {
            acc[0] = plain_eval<true>(348,   704855, cx, cy, cz, feats);
            acc[1] = plain_eval<true>(512,   835927, cx, cy, cz, feats);
            acc[2] = plain_eval<true>(753,   966999, cx, cy, cz, feats);
            acc[3] = plain_eval<true>(1108, 1098071, cx, cy, cz, feats);
            acc[4] = plain_eval<true>(1629, 1229143, cx, cy, cz, feats);
            acc[5] = plain_eval<true>(2394, 1360215, cx, cy, cz, feats);
        }
        vf4* o = (vf4*)(out + (size_t)n * 32);
        o[4] = (vf4){acc[0].x, acc[0].y, acc[1].x, acc[1].y};
        o[5] = (vf4){acc[2].x, acc[2].y, acc[3].x, acc[3].y};
        o[6] = (vf4){acc[4].x, acc[4].y, acc[5].x, acc[5].y};
    } else if (b < 4096) {
        // ---- L14: 2 threads/point, 4 corners each
        const int t = (b - 2048) * 256 + tid;
        const int n = t >> 1, half = t & 1;
        const float cx = coords[3*n+0], cy = coords[3*n+1], cz = coords[3*n+2];
        float a0, a1, ag;
        if (PACKED) {
            splash14_part(half * 4, cx, cy, cz, cx - 0.5f, cy - 0.5f, cz - 0.5f,
                          (const h8*)(ws + 2621440), a0, a1, ag);
        } else {
            splash_direct_part<2,4>(half * 4, 3520, 1491287, 0, cx, cy, cz,
                                    feats, means, stds, a0, a1, ag);
        }
        a0 += __shfl_xor(a0, 1);
        a1 += __shfl_xor(a1, 1);
        ag += __shfl_xor(ag, 1);
        if (!half) {
            *(float2*)(out + (size_t)n * 32 + 28) = make_float2(a0, a1);
            gmm[2 * n] = ag;
        }
    } else {
        // ---- L15: 4 threads/point, 2 corners each
        const int t = (b - 4096) * 256 + tid;
        const int n = t >> 2, q = t & 3;
        const float cx = coords[3*n+0], cy = coords[3*n+1], cz = coords[3*n+2];
        float a0, a1, ag;
        if (PACKED) {
            splash15_part(q * 2, cx, cy, cz, cx - 0.5f, cy - 0.5f, cz - 0.5f,
                          (const h8*)(ws + 4718592), a0, a1, ag);
        } else {
            splash_direct_part<4,2>(q * 2, 5174, 1753431, 262144, cx, cy, cz,
                                    feats, means, stds, a0, a1, ag);
        }
        a0 += __shfl_xor(a0, 1);
        a1 += __shfl_xor(a1, 1);
        ag += __shfl_xor(ag, 1);
        a0 += __shfl_xor(a0, 2);
        a1 += __shfl_xor(a1, 2);
        ag += __shfl_xor(ag, 2);
        if (q == 0) {
            *(float2*)(out + (size_t)n * 32 + 30) = make_float2(a0, a1);
            gmm[2 * n + 1] = ag;
        }
    }
}

extern "C" void kernel_launch(void* const* d_in, const int* in_sizes, int n_in,
                              void* d_out, int out_size, void* d_ws, size_t ws_size,
                              hipStream_t stream) {
    const float* coords = (const float*)d_in[0];
    const float* feats  = (const float*)d_in[1];
    const float* means  = (const float*)d_in[2];
    const float* stds   = (const float*)d_in[3];
    float* out = (float*)d_out;
    const int N = in_sizes[0] / 3;   // 262144

    const bool packed = (ws_size >= 17825792);   // 5MB plain + 4MB L14 + 8MB L15
    if (packed) {
        repack_kernel<<<6144, 256, 0, stream>>>(means, stds, feats, (_Float16*)d_ws);
        splash_enc<true><<<8192, 256, 0, stream>>>(coords, feats, means, stds,
                                                   (const _Float16*)d_ws, out, N);
    } else {
        splash_enc<false><<<8192, 256, 0, stream>>>(coords, feats, means, stds,
                                                    (const _Float16*)d_ws, out, N);
    }
}

// Round 7
// 233.338 us; speedup vs baseline: 2.7769x; 1.0265x over previous
//
#include <hip/hip_runtime.h>
#include <math.h>

// SplashEncoding: 16-level hash grid, trilinear interp; levels 14/15 add
// Gaussian splash mixtures (ns=2/4) feeding both feature and GMM outputs.
//
// R7 vs R6 (156us main; 70% of txns in pop0/pop1 long serial chains):
//  split EVERY phase across threads (R6 only split splash):
//    pop0: 4 thr/pt, thread q does linear level q + hashed level q+4
//          (uniform path: every lane 1 fp32-linear + 1 fp16-hashed eval)
//    pop1: 3 thr/pt, levels {8+q, 11+q} (magic div by 3)
//    L14:  4 thr/pt, 2 corners each, shfl-xor reduce over 4 lanes
//    L15:  8 thr/pt, 1 corner each,  shfl-xor reduce over 8 lanes
//  chains: 64->16, 48->16, 8->4, 8->4 txns. Phase/cache separation kept
//  (R5 win). fp16 tables + precomputed reciprocals kept (R4-R6 wins).

#define HMASK 131071
typedef float vf4 __attribute__((ext_vector_type(4)));
typedef _Float16 h8 __attribute__((ext_vector_type(8)));
typedef _Float16 h2 __attribute__((ext_vector_type(2)));

// fbases (float2 rows) of hashed plain levels 4..13 (for repack + fallback)
__constant__ int c_fbh[10] = {180567,311639,442711,573783,704855,835927,
                              966999,1098071,1229143,1360215};
// pop0 per-q: linear levels 0..3, hashed levels 4..7
__constant__ int c_lres[4] = {16,23,34,50};
__constant__ int c_lfb[4]  = {0,4096,16263,55567};
__constant__ int c_h0res[4] = {74,109,161,237};
// pop1 per-q: levels 8+q and 11+q
__constant__ int c_p1resA[3] = {348,512,753};
__constant__ int c_p1resB[3] = {1108,1629,2394};

__device__ __forceinline__ void corner_setup(int res, float cx, float cy, float cz,
                                             int& px, int& py, int& pz,
                                             float& fx, float& fy, float& fz)
{
    const float hi = (float)res - 1.001f;            // matches jnp.clip(res*c, 0, res-1.001)
    float x = fminf(fmaxf((float)res * cx, 0.0f), hi);
    float y = fminf(fmaxf((float)res * cy, 0.0f), hi);
    float z = fminf(fmaxf((float)res * cz, 0.0f), hi);
    px = (int)x; py = (int)y; pz = (int)z;           // >=0 so trunc == floor
    fx = x - (float)px; fy = y - (float)py; fz = z - (float)pz;
}

// fp32 plain level (linear or hashed fallback)
template<bool HASH>
__device__ __forceinline__ float2 plain_eval(
    int res, int fbase, float cx, float cy, float cz,
    const float* __restrict__ feats)
{
    int px, py, pz; float fx, fy, fz;
    corner_setup(res, cx, cy, cz, px, py, pz, fx, fy, fz);
    int   idxs[8];
    float ws[8];
#pragma unroll
    for (int k = 0; k < 8; ++k) {
        const int ox = (k >> 2) & 1, oy = (k >> 1) & 1, oz = k & 1;
        const int ix = px + ox, iy = py + oy, iz = pz + oz;
        ws[k] = (ox ? fx : 1.0f - fx) * (oy ? fy : 1.0f - fy) * (oz ? fz : 1.0f - fz);
        if (HASH) {
            unsigned h = (unsigned)ix ^ ((unsigned)iy * 2654435761u) ^ ((unsigned)iz * 805459861u);
            idxs[k] = (int)(h & HMASK);
        } else {
            idxs[k] = ix + iy * res + iz * res * res;
        }
    }
    float2 fv[8];
#pragma unroll
    for (int k = 0; k < 8; ++k)
        fv[k] = *(const float2*)(feats + (size_t)(fbase + idxs[k]) * 2);
    float a0 = 0.0f, a1 = 0.0f;
#pragma unroll
    for (int k = 0; k < 8; ++k) { a0 += ws[k] * fv[k].x; a1 += ws[k] * fv[k].y; }
    return make_float2(a0, a1);
}

// fp16 hashed plain level (4B/entry table in ws)
__device__ __forceinline__ float2 plain_eval_h(
    int res, const h2* __restrict__ tab, float cx, float cy, float cz)
{
    int px, py, pz; float fx, fy, fz;
    corner_setup(res, cx, cy, cz, px, py, pz, fx, fy, fz);
    int   idxs[8];
    float ws[8];
#pragma unroll
    for (int k = 0; k < 8; ++k) {
        const int ox = (k >> 2) & 1, oy = (k >> 1) & 1, oz = k & 1;
        const int ix = px + ox, iy = py + oy, iz = pz + oz;
        ws[k] = (ox ? fx : 1.0f - fx) * (oy ? fy : 1.0f - fy) * (oz ? fz : 1.0f - fz);
        unsigned h = (unsigned)ix ^ ((unsigned)iy * 2654435761u) ^ ((unsigned)iz * 805459861u);
        idxs[k] = (int)(h & HMASK);
    }
    h2 fv[8];
#pragma unroll
    for (int k = 0; k < 8; ++k) fv[k] = tab[idxs[k]];
    float a0 = 0.0f, a1 = 0.0f;
#pragma unroll
    for (int k = 0; k < 8; ++k) { a0 += ws[k] * (float)fv[k][0]; a1 += ws[k] * (float)fv[k][1]; }
    return make_float2(a0, a1);
}

__device__ __forceinline__ void gauss_pre(float w, float dx, float dy, float dz,
                                          float i2s, float inrm, float is2,
                                          float f0, float f1,
                                          float& a0, float& a1, float& ag)
{
    const float d2 = dx*dx + dy*dy + dz*dz;
    const float sq = d2 * i2s;
    const float gw = __expf(-sq) * inrm;
    const float wg = w * gw;
    a0 += wg * f0;
    a1 += wg * f1;
    ag += wg * (d2 * is2);
}

// L14 packed slot (32B = 2 h8):
//   A: mo0.xyz mo1.xyz i2s0 i2s1      B: inrm0 inrm1 is20 is21 f00 f01 f10 f11
// corners [k0, k0+2)
__device__ __forceinline__ void splash14_part(
    int k0, float cx, float cy, float cz, float cox, float coy, float coz,
    const h8* __restrict__ slots, float& a0, float& a1, float& ag)
{
    int px, py, pz; float fx, fy, fz;
    corner_setup(3520, cx, cy, cz, px, py, pz, fx, fy, fz);
    a0 = 0.0f; a1 = 0.0f; ag = 0.0f;
#pragma unroll
    for (int kk = 0; kk < 2; ++kk) {
        const int k = k0 + kk;
        const int ox = (k >> 2) & 1, oy = (k >> 1) & 1, oz = k & 1;
        const int ix = px + ox, iy = py + oy, iz = pz + oz;
        const float w = (ox ? fx : 1.0f - fx) * (oy ? fy : 1.0f - fy) * (oz ? fz : 1.0f - fz);
        unsigned h = (unsigned)ix ^ ((unsigned)iy * 2654435761u) ^ ((unsigned)iz * 805459861u);
        const int idx = (int)(h & HMASK);
        const h8* sp = slots + (size_t)idx * 2;
        h8 A = sp[0], B = sp[1];
        gauss_pre(w, cox - (float)A[0], coy - (float)A[1], coz - (float)A[2],
                  (float)A[6], (float)B[0], (float)B[2], (float)B[4], (float)B[5], a0, a1, ag);
        gauss_pre(w, cox - (float)A[3], coy - (float)A[4], coz - (float)A[5],
                  (float)A[7], (float)B[1], (float)B[3], (float)B[6], (float)B[7], a0, a1, ag);
    }
}

// L15 packed slot (64B = 4 h8 = ONE cache line):
//   A: mo[0..7]   B: mo[8..11] i2s[0..3]   C: inrm[0..3] is2[0..3]   D: f[0..7]
// single corner k
__device__ __forceinline__ void splash15_part(
    int k, float cx, float cy, float cz, float cox, float coy, float coz,
    const h8* __restrict__ slots, float& a0, float& a1, float& ag)
{
    int px, py, pz; float fx, fy, fz;
    corner_setup(5174, cx, cy, cz, px, py, pz, fx, fy, fz);
    a0 = 0.0f; a1 = 0.0f; ag = 0.0f;
    const int ox = (k >> 2) & 1, oy = (k >> 1) & 1, oz = k & 1;
    const int ix = px + ox, iy = py + oy, iz = pz + oz;
    const float w = (ox ? fx : 1.0f - fx) * (oy ? fy : 1.0f - fy) * (oz ? fz : 1.0f - fz);
    unsigned h = (unsigned)ix ^ ((unsigned)iy * 2654435761u) ^ ((unsigned)iz * 805459861u);
    const int idx = (int)(h & HMASK);
    const h8* sp = slots + (size_t)idx * 4;
    h8 A = sp[0], B = sp[1], C = sp[2], D = sp[3];
    gauss_pre(w, cox - (float)A[0], coy - (float)A[1], coz - (float)A[2],
              (float)B[4], (float)C[0], (float)C[4], (float)D[0], (float)D[1], a0, a1, ag);
    gauss_pre(w, cox - (float)A[3], coy - (float)A[4], coz - (float)A[5],
              (float)B[5], (float)C[1], (float)C[5], (float)D[2], (float)D[3], a0, a1, ag);
    gauss_pre(w, cox - (float)A[6], coy - (float)A[7], coz - (float)B[0],
              (float)B[6], (float)C[2], (float)C[6], (float)D[4], (float)D[5], a0, a1, ag);
    gauss_pre(w, cox - (float)B[1], coy - (float)B[2], coz - (float)B[3],
              (float)B[7], (float)C[3], (float)C[7], (float)D[6], (float)D[7], a0, a1, ag);
}

// fallback splash (direct fp32 table loads), corner range [k0, k0+KN)
template<int NS, int KN>
__device__ __forceinline__ void splash_direct_part(
    int k0, int res, int fbase, int gbase, float cx, float cy, float cz,
    const float* __restrict__ feats, const float* __restrict__ means,
    const float* __restrict__ stds, float& a0, float& a1, float& ag)
{
    int px, py, pz; float fx, fy, fz;
    corner_setup(res, cx, cy, cz, px, py, pz, fx, fy, fz);
    a0 = 0.0f; a1 = 0.0f; ag = 0.0f;
#pragma unroll
    for (int kk = 0; kk < KN; ++kk) {
        const int k = k0 + kk;
        const int ox = (k >> 2) & 1, oy = (k >> 1) & 1, oz = k & 1;
        const int ix = px + ox, iy = py + oy, iz = pz + oz;
        const float w = (ox ? fx : 1.0f - fx) * (oy ? fy : 1.0f - fy) * (oz ? fz : 1.0f - fz);
        unsigned h = (unsigned)ix ^ ((unsigned)iy * 2654435761u) ^ ((unsigned)iz * 805459861u);
        const int idx = (int)(h & HMASK);
        const int grow = gbase + idx * NS;
        const float* m = means + (size_t)grow * 3;
        const float* s = stds + grow;
        const float* f = feats + (size_t)(fbase + idx * NS) * 2;
#pragma unroll
        for (int si = 0; si < NS; ++si) {
            const float dx = cx - m[3*si], dy = cy - m[3*si+1], dz = cz - m[3*si+2];
            const float sva = fabsf(s[si]);
            const float d2 = dx*dx + dy*dy + dz*dz;
            const float s2 = sva * sva;
            const float sq = d2 / (2.0f * s2 + 1e-7f);
            const float gw = expf(-sq) / (2.5066282746310002f * sva + 1e-7f);
            const float wg = w * gw;
            a0 += wg * f[2*si];
            a1 += wg * f[2*si+1];
            ag += wg * (d2 / s2);
        }
    }
}

// ws layout (in halfs):
//   [0, 2621440)        : levels 4-13 fp16 feat tables, 262144 halfs each
//   [2621440, 4718592)  : L14 slots (16 halfs each)
//   [4718592, 8912896)  : L15 slots (32 halfs each)
__global__ __launch_bounds__(256) void repack_kernel(
    const float* __restrict__ means, const float* __restrict__ stds,
    const float* __restrict__ feats, _Float16* __restrict__ ws)
{
    const int i = blockIdx.x * 256 + threadIdx.x;     // 0 .. 1572863
    if (i < 1310720) {
        // plain hashed levels 4-13: fp16 feats
        const int lvl = i >> 17;            // /131072
        const int e   = i & 131071;
        const float2 f = *(const float2*)(feats + (size_t)(c_fbh[lvl] + e) * 2);
        h2 v; v[0] = (_Float16)f.x; v[1] = (_Float16)f.y;
        ((h2*)ws)[lvl * 131072 + e] = v;
    } else if (i < 1441792) {
        // level 14: ns=2, gbase=0, fbase=1491287
        const int e = i - 1310720;
        const float2* m2 = (const float2*)(means + (size_t)e * 6);       // 8B-aligned
        const float2 ma = m2[0], mb = m2[1], mc = m2[2];
        const float2 sv = *(const float2*)(stds + 2 * e);
        const float2* f2 = (const float2*)(feats + (size_t)(1491287 + 2 * e) * 2);
        const float2 fa = f2[0], fb = f2[1];
        const float s0 = fabsf(sv.x), s1 = fabsf(sv.y);
        h8 A, B;
        A[0] = (_Float16)(ma.x - 0.5f); A[1] = (_Float16)(ma.y - 0.5f); A[2] = (_Float16)(mb.x - 0.5f);
        A[3] = (_Float16)(mb.y - 0.5f); A[4] = (_Float16)(mc.x - 0.5f); A[5] = (_Float16)(mc.y - 0.5f);
        A[6] = (_Float16)(1.0f / (2.0f * s0 * s0 + 1e-7f));
        A[7] = (_Float16)(1.0f / (2.0f * s1 * s1 + 1e-7f));
        B[0] = (_Float16)(1.0f / (2.5066282746310002f * s0 + 1e-7f));
        B[1] = (_Float16)(1.0f / (2.5066282746310002f * s1 + 1e-7f));
        B[2] = (_Float16)(1.0f / (s0 * s0));
        B[3] = (_Float16)(1.0f / (s1 * s1));
        B[4] = (_Float16)fa.x; B[5] = (_Float16)fa.y; B[6] = (_Float16)fb.x; B[7] = (_Float16)fb.y;
        h8* dst = (h8*)(ws + 2621440) + (size_t)e * 2;
        dst[0] = A; dst[1] = B;
    } else {
        // level 15: ns=4, gbase=262144, fbase=1753431
        const int e = i - 1441792;
        const vf4* m4 = (const vf4*)(means + (size_t)(262144 + 4 * e) * 3); // 16B-aligned
        const vf4 u = m4[0], v = m4[1], w = m4[2];
        const vf4 s4 = *(const vf4*)(stds + 262144 + 4 * e);                // 16B-aligned
        const float2* f2 = (const float2*)(feats + (size_t)(1753431 + 4 * e) * 2);
        const float2 fa = f2[0], fb = f2[1], fc = f2[2], fd = f2[3];
        h8 A, B, C, D;
        A[0] = (_Float16)(u.x - 0.5f); A[1] = (_Float16)(u.y - 0.5f); A[2] = (_Float16)(u.z - 0.5f);
        A[3] = (_Float16)(u.w - 0.5f); A[4] = (_Float16)(v.x - 0.5f); A[5] = (_Float16)(v.y - 0.5f);
        A[6] = (_Float16)(v.z - 0.5f); A[7] = (_Float16)(v.w - 0.5f);
        B[0] = (_Float16)(w.x - 0.5f); B[1] = (_Float16)(w.y - 0.5f);
        B[2] = (_Float16)(w.z - 0.5f); B[3] = (_Float16)(w.w - 0.5f);
        const float sv[4] = {fabsf(s4.x), fabsf(s4.y), fabsf(s4.z), fabsf(s4.w)};
#pragma unroll
        for (int t = 0; t < 4; ++t) {
            B[4 + t] = (_Float16)(1.0f / (2.0f * sv[t] * sv[t] + 1e-7f));
            C[t]     = (_Float16)(1.0f / (2.5066282746310002f * sv[t] + 1e-7f));
            C[4 + t] = (_Float16)(1.0f / (sv[t] * sv[t]));
        }
        D[0] = (_Float16)fa.x; D[1] = (_Float16)fa.y; D[2] = (_Float16)fb.x; D[3] = (_Float16)fb.y;
        D[4] = (_Float16)fc.x; D[5] = (_Float16)fc.y; D[6] = (_Float16)fd.x; D[7] = (_Float16)fd.y;
        h8* dst = (h8*)(ws + 4718592) + (size_t)e * 4;
        dst[0] = A; dst[1] = B; dst[2] = C; dst[3] = D;
    }
}

// grid: [0,4096) pop0 lv0-7 4thr/pt | [4096,7168) pop1 lv8-13 3thr/pt |
//       [7168,11264) L14 4thr/pt | [11264,19456) L15 8thr/pt
template<bool PACKED>
__global__ __launch_bounds__(256) void splash_enc(
    const float* __restrict__ coords, const float* __restrict__ feats,
    const float* __restrict__ means,  const float* __restrict__ stds,
    const _Float16* __restrict__ ws, float* __restrict__ out, int N)
{
    const int b = blockIdx.x;
    const int tid = threadIdx.x;
    const h2* tabs = (const h2*)ws;   // level L in [4,13]: tabs + (L-4)*131072
    float* gmm = out + (size_t)N * 32;

    if (b < 4096) {
        // ---- pop0: levels 0-7, thread q: linear level q + hashed level q+4
        const int t = b * 256 + tid;
        const int n = t >> 2, q = t & 3;
        const float cx = coords[3*n+0], cy = coords[3*n+1], cz = coords[3*n+2];
        float2 rlin = plain_eval<false>(c_lres[q], c_lfb[q], cx, cy, cz, feats);
        float2 rhsh;
        if (PACKED) rhsh = plain_eval_h(c_h0res[q], tabs + q * 131072, cx, cy, cz);
        else        rhsh = plain_eval<true>(c_h0res[q], c_fbh[q], cx, cy, cz, feats);
        *(float2*)(out + (size_t)n * 32 + 2 * q)     = rlin;
        *(float2*)(out + (size_t)n * 32 + 8 + 2 * q) = rhsh;
    } else if (b < 7168) {
        // ---- pop1: levels 8-13, thread q: levels 8+q and 11+q
        const int t = (b - 4096) * 256 + tid;               // [0, 786432)
        const int n = (int)(((unsigned long long)(unsigned)t * 0xAAAAAAABull) >> 33);
        const int q = t - 3 * n;
        const float cx = coords[3*n+0], cy = coords[3*n+1], cz = coords[3*n+2];
        float2 rA, rB;
        if (PACKED) {
            rA = plain_eval_h(c_p1resA[q], tabs + (4 + q) * 131072, cx, cy, cz);
            rB = plain_eval_h(c_p1resB[q], tabs + (7 + q) * 131072, cx, cy, cz);
        } else {
            rA = plain_eval<true>(c_p1resA[q], c_fbh[4 + q], cx, cy, cz, feats);
            rB = plain_eval<true>(c_p1resB[q], c_fbh[7 + q], cx, cy, cz, feats);
        }
        *(float2*)(out + (size_t)n * 32 + 16 + 2 * q) = rA;
        *(float2*)(out + (size_t)n * 32 + 22 + 2 * q) = rB;
    } else if (b < 11264) {
        // ---- L14: 4 threads/point, 2 corners each
        const int t = (b - 7168) * 256 + tid;
        const int n = t >> 2, q = t & 3;
        const float cx = coords[3*n+0], cy = coords[3*n+1], cz = coords[3*n+2];
        float a0, a1, ag;
        if (PACKED) {
            splash14_part(q * 2, cx, cy, cz, cx - 0.5f, cy - 0.5f, cz - 0.5f,
                          (const h8*)(ws + 2621440), a0, a1, ag);
        } else {
            splash_direct_part<2,2>(q * 2, 3520, 1491287, 0, cx, cy, cz,
                                    feats, means, stds, a0, a1, ag);
        }
        a0 += __shfl_xor(a0, 1); a1 += __shfl_xor(a1, 1); ag += __shfl_xor(ag, 1);
        a0 += __shfl_xor(a0, 2); a1 += __shfl_xor(a1, 2); ag += __shfl_xor(ag, 2);
        if (q == 0) {
            *(float2*)(out + (size_t)n * 32 + 28) = make_float2(a0, a1);
            gmm[2 * n] = ag;
        }
    } else {
        // ---- L15: 8 threads/point, 1 corner each
        const int t = (b - 11264) * 256 + tid;
        const int n = t >> 3, q = t & 7;
        const float cx = coords[3*n+0], cy = coords[3*n+1], cz = coords[3*n+2];
        float a0, a1, ag;
        if (PACKED) {
            splash15_part(q, cx, cy, cz, cx - 0.5f, cy - 0.5f, cz - 0.5f,
                          (const h8*)(ws + 4718592), a0, a1, ag);
        } else {
            splash_direct_part<4,1>(q, 5174, 1753431, 262144, cx, cy, cz,
                                    feats, means, stds, a0, a1, ag);
        }
        a0 += __shfl_xor(a0, 1); a1 += __shfl_xor(a1, 1); ag += __shfl_xor(ag, 1);
        a0 += __shfl_xor(a0, 2); a1 += __shfl_xor(a1, 2); ag += __shfl_xor(ag, 2);
        a0 += __shfl_xor(a0, 4); a1 += __shfl_xor(a1, 4); ag += __shfl_xor(ag, 4);
        if (q == 0) {
            *(float2*)(out + (size_t)n * 32 + 30) = make_float2(a0, a1);
            gmm[2 * n + 1] = ag;
        }
    }
}

extern "C" void kernel_launch(void* const* d_in, const int* in_sizes, int n_in,
                              void* d_out, int out_size, void* d_ws, size_t ws_size,
                              hipStream_t stream) {
    const float* coords = (const float*)d_in[0];
    const float* feats  = (const float*)d_in[1];
    const float* means  = (const float*)d_in[2];
    const float* stds   = (const float*)d_in[3];
    float* out = (float*)d_out;
    const int N = in_sizes[0] / 3;   // 262144

    const bool packed = (ws_size >= 17825792);   // 5MB plain + 4MB L14 + 8MB L15
    if (packed) {
        repack_kernel<<<6144, 256, 0, stream>>>(means, stds, feats, (_Float16*)d_ws);
        splash_enc<true><<<19456, 256, 0, stream>>>(coords, feats, means, stds,
                                                    (const _Float16*)d_ws, out, N);
    } else {
        splash_enc<false><<<19456, 256, 0, stream>>>(coords, feats, means, stds,
                                                     (const _Float16*)d_ws, out, N);
    }
}

// Round 8
// 221.949 us; speedup vs baseline: 2.9194x; 1.0513x over previous
//
#include <hip/hip_runtime.h>
#include <math.h>

// SplashEncoding: 16-level hash grid, trilinear interp; levels 14/15 add
// Gaussian splash mixtures (ns=2/4) feeding both feature and GMM outputs.
//
// R8 vs R7 (148.6us main; ~2.2 cyc/line-touch = near gather-throughput wall):
//  - linear levels 0-3: corner pairs (k,k+4) are ADJACENT entries (x is the
//    unit-stride dim) -> one float4 load covers both corners: 8->4 txns/level.
//    Total txns 42M -> 37.8M (-10%).
//  - repack: 4 plain entries/thread (float4 reads, 8B stores), fewer threads.
//  - everything else kept: phase/cache separation (R5), split-across-threads
//    MLP (R6/R7), fp16 tables + precomputed reciprocals (R4), full-line
//    writes (R3).

#define HMASK 131071
typedef float vf4 __attribute__((ext_vector_type(4)));
typedef _Float16 h8 __attribute__((ext_vector_type(8)));
typedef _Float16 h4 __attribute__((ext_vector_type(4)));
typedef _Float16 h2 __attribute__((ext_vector_type(2)));

// fbases (float2 rows) of hashed plain levels 4..13 (for repack + fallback)
__constant__ int c_fbh[10] = {180567,311639,442711,573783,704855,835927,
                              966999,1098071,1229143,1360215};
// pop0 per-q: linear levels 0..3, hashed levels 4..7
__constant__ int c_lres[4] = {16,23,34,50};
__constant__ int c_lfb[4]  = {0,4096,16263,55567};
__constant__ int c_h0res[4] = {74,109,161,237};
// pop1 per-q: levels 8+q and 11+q
__constant__ int c_p1resA[3] = {348,512,753};
__constant__ int c_p1resB[3] = {1108,1629,2394};

__device__ __forceinline__ void corner_setup(int res, float cx, float cy, float cz,
                                             int& px, int& py, int& pz,
                                             float& fx, float& fy, float& fz)
{
    const float hi = (float)res - 1.001f;            // matches jnp.clip(res*c, 0, res-1.001)
    float x = fminf(fmaxf((float)res * cx, 0.0f), hi);
    float y = fminf(fmaxf((float)res * cy, 0.0f), hi);
    float z = fminf(fmaxf((float)res * cz, 0.0f), hi);
    px = (int)x; py = (int)y; pz = (int)z;           // >=0 so trunc == floor
    fx = x - (float)px; fy = y - (float)py; fz = z - (float)pz;
}

// linear level: 4 float4 gathers (each covers the ox=0/1 corner pair)
__device__ __forceinline__ float2 linear_eval4(
    int res, int fbase, float cx, float cy, float cz,
    const float* __restrict__ feats)
{
    int px, py, pz; float fx, fy, fz;
    corner_setup(res, cx, cy, cz, px, py, pz, fx, fy, fz);
    // j = (oy<<1)|oz; base corner (ox=0): idx = px + (py+oy)*res + (pz+oz)*res^2
    int idxs[4]; float wyz[4];
#pragma unroll
    for (int j = 0; j < 4; ++j) {
        const int oy = (j >> 1) & 1, oz = j & 1;
        idxs[j] = px + (py + oy) * res + (pz + oz) * res * res;
        wyz[j] = (oy ? fy : 1.0f - fy) * (oz ? fz : 1.0f - fz);
    }
    vf4 fv[4];
#pragma unroll
    for (int j = 0; j < 4; ++j)
        fv[j] = *(const vf4*)(feats + (size_t)(fbase + idxs[j]) * 2);  // 8B-aligned ok
    float a0 = 0.0f, a1 = 0.0f;
    const float gx = 1.0f - fx;
#pragma unroll
    for (int j = 0; j < 4; ++j) {
        a0 += wyz[j] * (gx * fv[j].x + fx * fv[j].z);
        a1 += wyz[j] * (gx * fv[j].y + fx * fv[j].w);
    }
    return make_float2(a0, a1);
}

// fp32 hashed plain level (fallback path)
__device__ __forceinline__ float2 plain_eval_f32h(
    int res, int fbase, float cx, float cy, float cz,
    const float* __restrict__ feats)
{
    int px, py, pz; float fx, fy, fz;
    corner_setup(res, cx, cy, cz, px, py, pz, fx, fy, fz);
    int   idxs[8];
    float ws[8];
#pragma unroll
    for (int k = 0; k < 8; ++k) {
        const int ox = (k >> 2) & 1, oy = (k >> 1) & 1, oz = k & 1;
        const int ix = px + ox, iy = py + oy, iz = pz + oz;
        ws[k] = (ox ? fx : 1.0f - fx) * (oy ? fy : 1.0f - fy) * (oz ? fz : 1.0f - fz);
        unsigned h = (unsigned)ix ^ ((unsigned)iy * 2654435761u) ^ ((unsigned)iz * 805459861u);
        idxs[k] = (int)(h & HMASK);
    }
    float2 fv[8];
#pragma unroll
    for (int k = 0; k < 8; ++k)
        fv[k] = *(const float2*)(feats + (size_t)(fbase + idxs[k]) * 2);
    float a0 = 0.0f, a1 = 0.0f;
#pragma unroll
    for (int k = 0; k < 8; ++k) { a0 += ws[k] * fv[k].x; a1 += ws[k] * fv[k].y; }
    return make_float2(a0, a1);
}

// fp16 hashed plain level (4B/entry table in ws)
__device__ __forceinline__ float2 plain_eval_h(
    int res, const h2* __restrict__ tab, float cx, float cy, float cz)
{
    int px, py, pz; float fx, fy, fz;
    corner_setup(res, cx, cy, cz, px, py, pz, fx, fy, fz);
    int   idxs[8];
    float ws[8];
#pragma unroll
    for (int k = 0; k < 8; ++k) {
        const int ox = (k >> 2) & 1, oy = (k >> 1) & 1, oz = k & 1;
        const int ix = px + ox, iy = py + oy, iz = pz + oz;
        ws[k] = (ox ? fx : 1.0f - fx) * (oy ? fy : 1.0f - fy) * (oz ? fz : 1.0f - fz);
        unsigned h = (unsigned)ix ^ ((unsigned)iy * 2654435761u) ^ ((unsigned)iz * 805459861u);
        idxs[k] = (int)(h & HMASK);
    }
    h2 fv[8];
#pragma unroll
    for (int k = 0; k < 8; ++k) fv[k] = tab[idxs[k]];
    float a0 = 0.0f, a1 = 0.0f;
#pragma unroll
    for (int k = 0; k < 8; ++k) { a0 += ws[k] * (float)fv[k][0]; a1 += ws[k] * (float)fv[k][1]; }
    return make_float2(a0, a1);
}

__device__ __forceinline__ void gauss_pre(float w, float dx, float dy, float dz,
                                          float i2s, float inrm, float is2,
                                          float f0, float f1,
                                          float& a0, float& a1, float& ag)
{
    const float d2 = dx*dx + dy*dy + dz*dz;
    const float sq = d2 * i2s;
    const float gw = __expf(-sq) * inrm;
    const float wg = w * gw;
    a0 += wg * f0;
    a1 += wg * f1;
    ag += wg * (d2 * is2);
}

// L14 packed slot (32B = 2 h8):
//   A: mo0.xyz mo1.xyz i2s0 i2s1      B: inrm0 inrm1 is20 is21 f00 f01 f10 f11
// corners [k0, k0+2)
__device__ __forceinline__ void splash14_part(
    int k0, float cx, float cy, float cz, float cox, float coy, float coz,
    const h8* __restrict__ slots, float& a0, float& a1, float& ag)
{
    int px, py, pz; float fx, fy, fz;
    corner_setup(3520, cx, cy, cz, px, py, pz, fx, fy, fz);
    a0 = 0.0f; a1 = 0.0f; ag = 0.0f;
#pragma unroll
    for (int kk = 0; kk < 2; ++kk) {
        const int k = k0 + kk;
        const int ox = (k >> 2) & 1, oy = (k >> 1) & 1, oz = k & 1;
        const int ix = px + ox, iy = py + oy, iz = pz + oz;
        const float w = (ox ? fx : 1.0f - fx) * (oy ? fy : 1.0f - fy) * (oz ? fz : 1.0f - fz);
        unsigned h = (unsigned)ix ^ ((unsigned)iy * 2654435761u) ^ ((unsigned)iz * 805459861u);
        const int idx = (int)(h & HMASK);
        const h8* sp = slots + (size_t)idx * 2;
        h8 A = sp[0], B = sp[1];
        gauss_pre(w, cox - (float)A[0], coy - (float)A[1], coz - (float)A[2],
                  (float)A[6], (float)B[0], (float)B[2], (float)B[4], (float)B[5], a0, a1, ag);
        gauss_pre(w, cox - (float)A[3], coy - (float)A[4], coz - (float)A[5],
                  (float)A[7], (float)B[1], (float)B[3], (float)B[6], (float)B[7], a0, a1, ag);
    }
}

// L15 packed slot (64B = 4 h8 = ONE cache line):
//   A: mo[0..7]   B: mo[8..11] i2s[0..3]   C: inrm[0..3] is2[0..3]   D: f[0..7]
// single corner k
__device__ __forceinline__ void splash15_part(
    int k, float cx, float cy, float cz, float cox, float coy, float coz,
    const h8* __restrict__ slots, float& a0, float& a1, float& ag)
{
    int px, py, pz; float fx, fy, fz;
    corner_setup(5174, cx, cy, cz, px, py, pz, fx, fy, fz);
    a0 = 0.0f; a1 = 0.0f; ag = 0.0f;
    const int ox = (k >> 2) & 1, oy = (k >> 1) & 1, oz = k & 1;
    const int ix = px + ox, iy = py + oy, iz = pz + oz;
    const float w = (ox ? fx : 1.0f - fx) * (oy ? fy : 1.0f - fy) * (oz ? fz : 1.0f - fz);
    unsigned h = (unsigned)ix ^ ((unsigned)iy * 2654435761u) ^ ((unsigned)iz * 805459861u);
    const int idx = (int)(h & HMASK);
    const h8* sp = slots + (size_t)idx * 4;
    h8 A = sp[0], B = sp[1], C = sp[2], D = sp[3];
    gauss_pre(w, cox - (float)A[0], coy - (float)A[1], coz - (float)A[2],
              (float)B[4], (float)C[0], (float)C[4], (float)D[0], (float)D[1], a0, a1, ag);
    gauss_pre(w, cox - (float)A[3], coy - (float)A[4], coz - (float)A[5],
              (float)B[5], (float)C[1], (float)C[5], (float)D[2], (float)D[3], a0, a1, ag);
    gauss_pre(w, cox - (float)A[6], coy - (float)A[7], coz - (float)B[0],
              (float)B[6], (float)C[2], (float)C[6], (float)D[4], (float)D[5], a0, a1, ag);
    gauss_pre(w, cox - (float)B[1], coy - (float)B[2], coz - (float)B[3],
              (float)B[7], (float)C[3], (float)C[7], (float)D[6], (float)D[7], a0, a1, ag);
}

// fallback splash (direct fp32 table loads), corner range [k0, k0+KN)
template<int NS, int KN>
__device__ __forceinline__ void splash_direct_part(
    int k0, int res, int fbase, int gbase, float cx, float cy, float cz,
    const float* __restrict__ feats, const float* __restrict__ means,
    const float* __restrict__ stds, float& a0, float& a1, float& ag)
{
    int px, py, pz; float fx, fy, fz;
    corner_setup(res, cx, cy, cz, px, py, pz, fx, fy, fz);
    a0 = 0.0f; a1 = 0.0f; ag = 0.0f;
#pragma unroll
    for (int kk = 0; kk < KN; ++kk) {
        const int k = k0 + kk;
        const int ox = (k >> 2) & 1, oy = (k >> 1) & 1, oz = k & 1;
        const int ix = px + ox, iy = py + oy, iz = pz + oz;
        const float w = (ox ? fx : 1.0f - fx) * (oy ? fy : 1.0f - fy) * (oz ? fz : 1.0f - fz);
        unsigned h = (unsigned)ix ^ ((unsigned)iy * 2654435761u) ^ ((unsigned)iz * 805459861u);
        const int idx = (int)(h & HMASK);
        const int grow = gbase + idx * NS;
        const float* m = means + (size_t)grow * 3;
        const float* s = stds + grow;
        const float* f = feats + (size_t)(fbase + idx * NS) * 2;
#pragma unroll
        for (int si = 0; si < NS; ++si) {
            const float dx = cx - m[3*si], dy = cy - m[3*si+1], dz = cz - m[3*si+2];
            const float sva = fabsf(s[si]);
            const float d2 = dx*dx + dy*dy + dz*dz;
            const float s2 = sva * sva;
            const float sq = d2 / (2.0f * s2 + 1e-7f);
            const float gw = expf(-sq) / (2.5066282746310002f * sva + 1e-7f);
            const float wg = w * gw;
            a0 += wg * f[2*si];
            a1 += wg * f[2*si+1];
            ag += wg * (d2 / s2);
        }
    }
}

// ws layout (in halfs):
//   [0, 2621440)        : levels 4-13 fp16 feat tables, 262144 halfs each
//   [2621440, 4718592)  : L14 slots (16 halfs each)
//   [4718592, 8912896)  : L15 slots (32 halfs each)
// repack threads: [0,327680) plain x4-entries | [327680,458752) L14 | [458752,589824) L15
__global__ __launch_bounds__(256) void repack_kernel(
    const float* __restrict__ means, const float* __restrict__ stds,
    const float* __restrict__ feats, _Float16* __restrict__ ws)
{
    const int i = blockIdx.x * 256 + threadIdx.x;     // 0 .. 589823
    if (i < 327680) {
        // plain hashed levels 4-13: fp16 feats, 4 entries per thread
        const int lvl = i >> 15;            // /32768
        const int e4  = (i & 32767) * 4;
        const float* src = feats + (size_t)(c_fbh[lvl] + e4) * 2;
        const vf4 fa = *(const vf4*)(src);      // entries e4, e4+1
        const vf4 fb = *(const vf4*)(src + 4);  // entries e4+2, e4+3
        h8 v;
        v[0] = (_Float16)fa.x; v[1] = (_Float16)fa.y; v[2] = (_Float16)fa.z; v[3] = (_Float16)fa.w;
        v[4] = (_Float16)fb.x; v[5] = (_Float16)fb.y; v[6] = (_Float16)fb.z; v[7] = (_Float16)fb.w;
        *(h8*)(ws + (size_t)lvl * 262144 + 2 * e4) = v;   // 16B store, aligned
    } else if (i < 458752) {
        // level 14: ns=2, gbase=0, fbase=1491287
        const int e = i - 327680;
        const float2* m2 = (const float2*)(means + (size_t)e * 6);       // 8B-aligned
        const float2 ma = m2[0], mb = m2[1], mc = m2[2];
        const float2 sv = *(const float2*)(stds + 2 * e);
        const float2* f2 = (const float2*)(feats + (size_t)(1491287 + 2 * e) * 2);
        const float2 fa = f2[0], fb = f2[1];
        const float s0 = fabsf(sv.x), s1 = fabsf(sv.y);
        h8 A, B;
        A[0] = (_Float16)(ma.x - 0.5f); A[1] = (_Float16)(ma.y - 0.5f); A[2] = (_Float16)(mb.x - 0.5f);
        A[3] = (_Float16)(mb.y - 0.5f); A[4] = (_Float16)(mc.x - 0.5f); A[5] = (_Float16)(mc.y - 0.5f);
        A[6] = (_Float16)(1.0f / (2.0f * s0 * s0 + 1e-7f));
        A[7] = (_Float16)(1.0f / (2.0f * s1 * s1 + 1e-7f));
        B[0] = (_Float16)(1.0f / (2.5066282746310002f * s0 + 1e-7f));
        B[1] = (_Float16)(1.0f / (2.5066282746310002f * s1 + 1e-7f));
        B[2] = (_Float16)(1.0f / (s0 * s0));
        B[3] = (_Float16)(1.0f / (s1 * s1));
        B[4] = (_Float16)fa.x; B[5] = (_Float16)fa.y; B[6] = (_Float16)fb.x; B[7] = (_Float16)fb.y;
        h8* dst = (h8*)(ws + 2621440) + (size_t)e * 2;
        dst[0] = A; dst[1] = B;
    } else {
        // level 15: ns=4, gbase=262144, fbase=1753431
        const int e = i - 458752;
        const vf4* m4 = (const vf4*)(means + (size_t)(262144 + 4 * e) * 3); // 16B-aligned
        const vf4 u = m4[0], v = m4[1], w = m4[2];
        const vf4 s4 = *(const vf4*)(stds + 262144 + 4 * e);                // 16B-aligned
        const float2* f2 = (const float2*)(feats + (size_t)(1753431 + 4 * e) * 2);
        const float2 fa = f2[0], fb = f2[1], fc = f2[2], fd = f2[3];
        h8 A, B, C, D;
        A[0] = (_Float16)(u.x - 0.5f); A[1] = (_Float16)(u.y - 0.5f); A[2] = (_Float16)(u.z - 0.5f);
        A[3] = (_Float16)(u.w - 0.5f); A[4] = (_Float16)(v.x - 0.5f); A[5] = (_Float16)(v.y - 0.5f);
        A[6] = (_Float16)(v.z - 0.5f); A[7] = (_Float16)(v.w - 0.5f);
        B[0] = (_Float16)(w.x - 0.5f); B[1] = (_Float16)(w.y - 0.5f);
        B[2] = (_Float16)(w.z - 0.5f); B[3] = (_Float16)(w.w - 0.5f);
        const float sv[4] = {fabsf(s4.x), fabsf(s4.y), fabsf(s4.z), fabsf(s4.w)};
#pragma unroll
        for (int t = 0; t < 4; ++t) {
            B[4 + t] = (_Float16)(1.0f / (2.0f * sv[t] * sv[t] + 1e-7f));
            C[t]     = (_Float16)(1.0f / (2.5066282746310002f * sv[t] + 1e-7f));
            C[4 + t] = (_Float16)(1.0f / (sv[t] * sv[t]));
        }
        D[0] = (_Float16)fa.x; D[1] = (_Float16)fa.y; D[2] = (_Float16)fb.x; D[3] = (_Float16)fb.y;
        D[4] = (_Float16)fc.x; D[5] = (_Float16)fc.y; D[6] = (_Float16)fd.x; D[7] = (_Float16)fd.y;
        h8* dst = (h8*)(ws + 4718592) + (size_t)e * 4;
        dst[0] = A; dst[1] = B; dst[2] = C; dst[3] = D;
    }
}

// grid: [0,4096) pop0 lv0-7 4thr/pt | [4096,7168) pop1 lv8-13 3thr/pt |
//       [7168,11264) L14 4thr/pt | [11264,19456) L15 8thr/pt
template<bool PACKED>
__global__ __launch_bounds__(256) void splash_enc(
    const float* __restrict__ coords, const float* __restrict__ feats,
    const float* __restrict__ means,  const float* __restrict__ stds,
    const _Float16* __restrict__ ws, float* __restrict__ out, int N)
{
    const int b = blockIdx.x;
    const int tid = threadIdx.x;
    const h2* tabs = (const h2*)ws;   // level L in [4,13]: tabs + (L-4)*131072
    float* gmm = out + (size_t)N * 32;

    if (b < 4096) {
        // ---- pop0: levels 0-7, thread q: linear level q (float4-merged
        //      corner pairs) + hashed level q+4
        const int t = b * 256 + tid;
        const int n = t >> 2, q = t & 3;
        const float cx = coords[3*n+0], cy = coords[3*n+1], cz = coords[3*n+2];
        float2 rlin = linear_eval4(c_lres[q], c_lfb[q], cx, cy, cz, feats);
        float2 rhsh;
        if (PACKED) rhsh = plain_eval_h(c_h0res[q], tabs + q * 131072, cx, cy, cz);
        else        rhsh = plain_eval_f32h(c_h0res[q], c_fbh[q], cx, cy, cz, feats);
        *(float2*)(out + (size_t)n * 32 + 2 * q)     = rlin;
        *(float2*)(out + (size_t)n * 32 + 8 + 2 * q) = rhsh;
    } else if (b < 7168) {
        // ---- pop1: levels 8-13, thread q: levels 8+q and 11+q
        const int t = (b - 4096) * 256 + tid;               // [0, 786432)
        const int n = (int)(((unsigned long long)(unsigned)t * 0xAAAAAAABull) >> 33);
        const int q = t - 3 * n;
        const float cx = coords[3*n+0], cy = coords[3*n+1], cz = coords[3*n+2];
        float2 rA, rB;
        if (PACKED) {
            rA = plain_eval_h(c_p1resA[q], tabs + (4 + q) * 131072, cx, cy, cz);
            rB = plain_eval_h(c_p1resB[q], tabs + (7 + q) * 131072, cx, cy, cz);
        } else {
            rA = plain_eval_f32h(c_p1resA[q], c_fbh[4 + q], cx, cy, cz, feats);
            rB = plain_eval_f32h(c_p1resB[q], c_fbh[7 + q], cx, cy, cz, feats);
        }
        *(float2*)(out + (size_t)n * 32 + 16 + 2 * q) = rA;
        *(float2*)(out + (size_t)n * 32 + 22 + 2 * q) = rB;
    } else if (b < 11264) {
        // ---- L14: 4 threads/point, 2 corners each
        const int t = (b - 7168) * 256 + tid;
        const int n = t >> 2, q = t & 3;
        const float cx = coords[3*n+0], cy = coords[3*n+1], cz = coords[3*n+2];
        float a0, a1, ag;
        if (PACKED) {
            splash14_part(q * 2, cx, cy, cz, cx - 0.5f, cy - 0.5f, cz - 0.5f,
                          (const h8*)(ws + 2621440), a0, a1, ag);
        } else {
            splash_direct_part<2,2>(q * 2, 3520, 1491287, 0, cx, cy, cz,
                                    feats, means, stds, a0, a1, ag);
        }
        a0 += __shfl_xor(a0, 1); a1 += __shfl_xor(a1, 1); ag += __shfl_xor(ag, 1);
        a0 += __shfl_xor(a0, 2); a1 += __shfl_xor(a1, 2); ag += __shfl_xor(ag, 2);
        if (q == 0) {
            *(float2*)(out + (size_t)n * 32 + 28) = make_float2(a0, a1);
            gmm[2 * n] = ag;
        }
    } else {
        // ---- L15: 8 threads/point, 1 corner each
        const int t = (b - 11264) * 256 + tid;
        const int n = t >> 3, q = t & 7;
        const float cx = coords[3*n+0], cy = coords[3*n+1], cz = coords[3*n+2];
        float a0, a1, ag;
        if (PACKED) {
            splash15_part(q, cx, cy, cz, cx - 0.5f, cy - 0.5f, cz - 0.5f,
                          (const h8*)(ws + 4718592), a0, a1, ag);
        } else {
            splash_direct_part<4,1>(q, 5174, 1753431, 262144, cx, cy, cz,
                                    feats, means, stds, a0, a1, ag);
        }
        a0 += __shfl_xor(a0, 1); a1 += __shfl_xor(a1, 1); ag += __shfl_xor(ag, 1);
        a0 += __shfl_xor(a0, 2); a1 += __shfl_xor(a1, 2); ag += __shfl_xor(ag, 2);
        a0 += __shfl_xor(a0, 4); a1 += __shfl_xor(a1, 4); ag += __shfl_xor(ag, 4);
        if (q == 0) {
            *(float2*)(out + (size_t)n * 32 + 30) = make_float2(a0, a1);
            gmm[2 * n + 1] = ag;
        }
    }
}

extern "C" void kernel_launch(void* const* d_in, const int* in_sizes, int n_in,
                              void* d_out, int out_size, void* d_ws, size_t ws_size,
                              hipStream_t stream) {
    const float* coords = (const float*)d_in[0];
    const float* feats  = (const float*)d_in[1];
    const float* means  = (const float*)d_in[2];
    const float* stds   = (const float*)d_in[3];
    float* out = (float*)d_out;
    const int N = in_sizes[0] / 3;   // 262144

    const bool packed = (ws_size >= 17825792);   // 5MB plain + 4MB L14 + 8MB L15
    if (packed) {
        repack_kernel<<<2304, 256, 0, stream>>>(means, stds, feats, (_Float16*)d_ws);
        splash_enc<true><<<19456, 256, 0, stream>>>(coords, feats, means, stds,
                                                    (const _Float16*)d_ws, out, N);
    } else {
        splash_enc<false><<<19456, 256, 0, stream>>>(coords, feats, means, stds,
                                                     (const _Float16*)d_ws, out, N);
    }
}